// Round 1
// baseline (997.349 us; speedup 1.0000x reference)
//
#include <hip/hip_runtime.h>
#include <hip/hip_bf16.h>

#define NNODES 50000
#define NEDGES 1600000
#define ETOT   (NNODES + NEDGES)
#define FIN    256
#define HC     128
#define NEG    0.2f

// ---------------- CSR build ----------------

__global__ void edge_pre(const int* __restrict__ ei, const float* __restrict__ ea,
                         float* __restrict__ lsum, float* __restrict__ lcnt,
                         int* __restrict__ deg, int E) {
    int i = blockIdx.x * blockDim.x + threadIdx.x;
    if (i < E) {
        int dst = ei[E + i];
        atomicAdd(&lsum[dst], ea[i]);
        atomicAdd(&lcnt[dst], 1.0f);
        atomicAdd(&deg[dst], 1);
    }
}

__global__ void loop_attr_k(const float* __restrict__ lsum, const float* __restrict__ lcnt,
                            float* __restrict__ lattr, int* __restrict__ deg, int n) {
    int i = blockIdx.x * blockDim.x + threadIdx.x;
    if (i < n) {
        lattr[i] = lsum[i] / fmaxf(lcnt[i], 1.0f);
        deg[i] += 1;  // self-loop
    }
}

__global__ void scan_block(const int* __restrict__ deg, int* __restrict__ out,
                           int* __restrict__ bsum, int n) {
    __shared__ int sh[256];
    int t = threadIdx.x;
    int i = blockIdx.x * 256 + t;
    int v = (i < n) ? deg[i] : 0;
    sh[t] = v;
    __syncthreads();
    for (int o = 1; o < 256; o <<= 1) {
        int a = (t >= o) ? sh[t - o] : 0;
        __syncthreads();
        sh[t] += a;
        __syncthreads();
    }
    if (i < n) out[i] = sh[t] - v;          // exclusive within block
    if (t == 255) bsum[blockIdx.x] = sh[255];
}

__global__ void scan_top(int* __restrict__ bsum, int nb) {
    __shared__ int sh[256];
    int t = threadIdx.x;
    int v = (t < nb) ? bsum[t] : 0;
    sh[t] = v;
    __syncthreads();
    for (int o = 1; o < 256; o <<= 1) {
        int a = (t >= o) ? sh[t - o] : 0;
        __syncthreads();
        sh[t] += a;
        __syncthreads();
    }
    if (t < nb) bsum[t] = sh[t] - v;        // exclusive
}

__global__ void scan_add(int* __restrict__ rp, int* __restrict__ cur,
                         const int* __restrict__ boff, int n, int etot) {
    int i = blockIdx.x * blockDim.x + threadIdx.x;
    if (i < n) {
        int v = rp[i] + boff[i >> 8];
        rp[i] = v;
        cur[i] = v;
    } else if (i == n) {
        rp[n] = etot;
    }
}

__global__ void scatter_k(const int* __restrict__ ei, const float* __restrict__ ea,
                          const float* __restrict__ lattr, int* __restrict__ cur,
                          int* __restrict__ csr_src, float* __restrict__ csr_ea,
                          int E, int n) {
    int i = blockIdx.x * blockDim.x + threadIdx.x;
    if (i < E + n) {
        int s, d; float a;
        if (i < E) { s = ei[i]; d = ei[E + i]; a = ea[i]; }
        else       { s = d = i - E; a = lattr[i - E]; }
        int pos = atomicAdd(&cur[d], 1);
        csr_src[pos] = s;
        csr_ea[pos] = a;
    }
}

// wedot[h] = sum_c We[h*32+c]*ae[h*32+c]  (layers 1,2: 4 heads; layer 3: scalar)
__global__ void wedot_k(const float* We1, const float* ae1,
                        const float* We2, const float* ae2,
                        const float* We3, const float* ae3,
                        float* __restrict__ wedot) {
    int t = threadIdx.x;  // 128
    float p1 = We1[t] * ae1[t];
    float p2 = We2[t] * ae2[t];
    for (int o = 16; o; o >>= 1) {
        p1 += __shfl_xor(p1, o, 32);
        p2 += __shfl_xor(p2, o, 32);
    }
    if ((t & 31) == 0) {
        wedot[t >> 5] = p1;
        wedot[4 + (t >> 5)] = p2;
    }
    if (t == 0) wedot[8] = We3[0] * ae3[0];
}

// ---------------- GEMM + ls/ld epilogue ----------------
// h = x @ W  (no bias), ls[n,h]=sum_c h*a_s, ld[n,h]=sum_c h*a_d
template <int K>
__global__ __launch_bounds__(128) void gemm_lsld(
        const float* __restrict__ x, const float* __restrict__ W,
        const float* __restrict__ a_s, const float* __restrict__ a_d,
        float* __restrict__ h, float* __restrict__ ls, float* __restrict__ ld_,
        int n) {
    const int ROWS = 16;
    __shared__ float xs[ROWS * 32];
    int t = threadIdx.x;  // 128 = output column
    int r0 = blockIdx.x * ROWS;

    float acc[ROWS];
#pragma unroll
    for (int r = 0; r < ROWS; r++) acc[r] = 0.f;

    for (int kc = 0; kc < K; kc += 32) {
        __syncthreads();
#pragma unroll
        for (int q = 0; q < 4; q++) {
            int idx = q * 128 + t;
            int row = idx >> 5, k = idx & 31;
            xs[idx] = (r0 + row < n) ? x[(size_t)(r0 + row) * K + kc + k] : 0.f;
        }
        __syncthreads();
#pragma unroll
        for (int kk = 0; kk < 32; kk++) {
            float w = W[(size_t)(kc + kk) * HC + t];
#pragma unroll
            for (int r = 0; r < ROWS; r++)
                acc[r] = fmaf(xs[r * 32 + kk], w, acc[r]);
        }
    }

    float sa = a_s[t], sd = a_d[t];
#pragma unroll
    for (int r = 0; r < ROWS; r++) {
        int row = r0 + r;
        if (row >= n) break;
        float v = acc[r];
        h[(size_t)row * HC + t] = v;
        float p = v * sa, q = v * sd;
        for (int o = 16; o; o >>= 1) {
            p += __shfl_xor(p, o, 32);
            q += __shfl_xor(q, o, 32);
        }
        if ((t & 31) == 0) {
            ls[row * 4 + (t >> 5)] = p;
            ld_[row * 4 + (t >> 5)] = q;
        }
    }
}

// ---------------- per-node softmax aggregation ----------------
template <bool RELU, bool FUSE3>
__global__ __launch_bounds__(128) void agg_k(
        const float* __restrict__ h, const float* __restrict__ ls,
        const float* __restrict__ ld_, const int* __restrict__ row_ptr,
        const int* __restrict__ csr_src, const float* __restrict__ csr_ea,
        const float* __restrict__ wedot, const float* __restrict__ bias,
        float* __restrict__ out, const float* __restrict__ W3,
        float* __restrict__ h3, int n) {
    int nid = blockIdx.x;
    int t = threadIdx.x, head = t >> 5, lane = t & 31;
    int beg = row_ptr[nid], end = row_ptr[nid + 1];
    float ldn = ld_[nid * 4 + head];
    float wd = wedot[head];

    // pass 1: per-head max (lane-parallel)
    float mx = -1e30f;
    for (int j = beg + lane; j < end; j += 32) {
        int s = csr_src[j];
        float lg = ls[s * 4 + head] + ldn + csr_ea[j] * wd;
        lg = lg > 0.f ? lg : NEG * lg;
        mx = fmaxf(mx, lg);
    }
    for (int o = 16; o; o >>= 1) mx = fmaxf(mx, __shfl_xor(mx, o, 32));

    // pass 2: exp/sum + weighted feature accumulation
    float sum = 0.f, acc = 0.f;
    for (int j = beg; j < end; j++) {
        int s = csr_src[j];
        float lg = ls[s * 4 + head] + ldn + csr_ea[j] * wd;
        lg = lg > 0.f ? lg : NEG * lg;
        float p = __expf(lg - mx);
        sum += p;
        acc = fmaf(p, h[(size_t)s * HC + t], acc);
    }
    float v = acc / (sum + 1e-16f) + bias[t];
    if (RELU) v = fmaxf(v, 0.f);
    out[(size_t)nid * HC + t] = v;

    if (FUSE3) {
        float p = v * W3[t];
        for (int o = 32; o; o >>= 1) p += __shfl_xor(p, o, 64);
        __shared__ float sh[2];
        if ((t & 63) == 0) sh[t >> 6] = p;
        __syncthreads();
        if (t == 0) h3[nid] = sh[0] + sh[1];
    }
}

// ---------------- layer 3 (1 head, 1 channel), wave per node ----------------
__global__ __launch_bounds__(256) void layer3_k(
        const float* __restrict__ h3, const int* __restrict__ row_ptr,
        const int* __restrict__ csr_src, const float* __restrict__ csr_ea,
        const float* __restrict__ wedot, const float* __restrict__ as3,
        const float* __restrict__ ad3, const float* __restrict__ b3,
        float* __restrict__ out, int n) {
    int wid = (blockIdx.x * blockDim.x + threadIdx.x) >> 6;
    int lane = threadIdx.x & 63;
    if (wid >= n) return;
    float A = as3[0], D = ad3[0], wd = wedot[8];
    int beg = row_ptr[wid], end = row_ptr[wid + 1];
    float hdn = h3[wid] * D;

    float mx = -1e30f;
    for (int j = beg + lane; j < end; j += 64) {
        float lg = h3[csr_src[j]] * A + hdn + csr_ea[j] * wd;
        lg = lg > 0.f ? lg : NEG * lg;
        mx = fmaxf(mx, lg);
    }
    for (int o = 32; o; o >>= 1) mx = fmaxf(mx, __shfl_xor(mx, o, 64));

    float sum = 0.f, num = 0.f;
    for (int j = beg + lane; j < end; j += 64) {
        float hv = h3[csr_src[j]];
        float lg = hv * A + hdn + csr_ea[j] * wd;
        lg = lg > 0.f ? lg : NEG * lg;
        float p = __expf(lg - mx);
        sum += p;
        num = fmaf(p, hv, num);
    }
    for (int o = 32; o; o >>= 1) {
        sum += __shfl_xor(sum, o, 64);
        num += __shfl_xor(num, o, 64);
    }
    if (lane == 0) out[wid] = num / (sum + 1e-16f) + b3[0];
}

// ---------------- launch ----------------

extern "C" void kernel_launch(void* const* d_in, const int* in_sizes, int n_in,
                              void* d_out, int out_size, void* d_ws, size_t ws_size,
                              hipStream_t stream) {
    const float* x   = (const float*)d_in[0];
    const int*   ei  = (const int*)d_in[1];
    const float* ea  = (const float*)d_in[2];
    const float* W1  = (const float*)d_in[3];
    const float* We1 = (const float*)d_in[4];
    const float* as1 = (const float*)d_in[5];
    const float* ad1 = (const float*)d_in[6];
    const float* ae1 = (const float*)d_in[7];
    const float* b1  = (const float*)d_in[8];
    const float* W2  = (const float*)d_in[9];
    const float* We2 = (const float*)d_in[10];
    const float* as2 = (const float*)d_in[11];
    const float* ad2 = (const float*)d_in[12];
    const float* ae2 = (const float*)d_in[13];
    const float* b2  = (const float*)d_in[14];
    const float* W3  = (const float*)d_in[15];
    const float* We3 = (const float*)d_in[16];
    const float* as3 = (const float*)d_in[17];
    const float* ad3 = (const float*)d_in[18];
    const float* ae3 = (const float*)d_in[19];
    const float* b3  = (const float*)d_in[20];

    const int N = NNODES, E = NEDGES, etot = ETOT;

    char* ws = (char*)d_ws;
    size_t o = 0;
    auto alloc = [&](size_t bytes) { size_t r = o; o = (o + bytes + 255) & ~(size_t)255; return r; };
    size_t o_deg   = alloc((size_t)N * 4);
    size_t o_lsum  = alloc((size_t)N * 4);
    size_t o_lcnt  = alloc((size_t)N * 4);
    size_t zero_span = o;                       // memset region
    size_t o_rp    = alloc((size_t)(N + 1) * 4);
    size_t o_cur   = alloc((size_t)N * 4);
    size_t o_bsum  = alloc(256 * 4);
    size_t o_wd    = alloc(16 * 4);
    size_t o_lattr = alloc((size_t)N * 4);
    size_t o_csrs  = alloc((size_t)etot * 4);
    size_t o_csre  = alloc((size_t)etot * 4);
    size_t o_ls    = alloc((size_t)N * 4 * 4);
    size_t o_ld    = alloc((size_t)N * 4 * 4);
    size_t o_h3    = alloc((size_t)N * 4);
    size_t o_bufA  = alloc((size_t)N * HC * 4);
    size_t o_bufB  = alloc((size_t)N * HC * 4);

    int*   deg   = (int*)(ws + o_deg);
    float* lsum  = (float*)(ws + o_lsum);
    float* lcnt  = (float*)(ws + o_lcnt);
    int*   rp    = (int*)(ws + o_rp);
    int*   cur   = (int*)(ws + o_cur);
    int*   bsum  = (int*)(ws + o_bsum);
    float* wd    = (float*)(ws + o_wd);
    float* lattr = (float*)(ws + o_lattr);
    int*   csrs  = (int*)(ws + o_csrs);
    float* csre  = (float*)(ws + o_csre);
    float* ls    = (float*)(ws + o_ls);
    float* ld_   = (float*)(ws + o_ld);
    float* h3    = (float*)(ws + o_h3);
    float* bufA  = (float*)(ws + o_bufA);
    float* bufB  = (float*)(ws + o_bufB);

    hipMemsetAsync(ws, 0, zero_span, stream);

    int nb = (N + 255) / 256;
    edge_pre<<<(E + 255) / 256, 256, 0, stream>>>(ei, ea, lsum, lcnt, deg, E);
    loop_attr_k<<<nb, 256, 0, stream>>>(lsum, lcnt, lattr, deg, N);
    scan_block<<<nb, 256, 0, stream>>>(deg, rp, bsum, N);
    scan_top<<<1, 256, 0, stream>>>(bsum, nb);
    scan_add<<<(N + 256) / 256, 256, 0, stream>>>(rp, cur, bsum, N, etot);
    scatter_k<<<(etot + 255) / 256, 256, 0, stream>>>(ei, ea, lattr, cur, csrs, csre, E, N);
    wedot_k<<<1, 128, 0, stream>>>(We1, ae1, We2, ae2, We3, ae3, wd);

    // layer 1
    gemm_lsld<FIN><<<(N + 15) / 16, 128, 0, stream>>>(x, W1, as1, ad1, bufA, ls, ld_, N);
    agg_k<true, false><<<N, 128, 0, stream>>>(bufA, ls, ld_, rp, csrs, csre, wd, b1,
                                              bufB, nullptr, nullptr, N);
    // layer 2 (+ fused layer-3 projection)
    gemm_lsld<HC><<<(N + 15) / 16, 128, 0, stream>>>(bufB, W2, as2, ad2, bufA, ls, ld_, N);
    agg_k<true, true><<<N, 128, 0, stream>>>(bufA, ls, ld_, rp, csrs, csre, wd + 4, b2,
                                             bufB, W3, h3, N);
    // layer 3
    layer3_k<<<(N * 64 + 255) / 256, 256, 0, stream>>>(h3, rp, csrs, csre, wd, as3, ad3, b3,
                                                       (float*)d_out, N);
}

// Round 2
// 764.540 us; speedup vs baseline: 1.3045x; 1.3045x over previous
//
#include <hip/hip_runtime.h>
#include <hip/hip_bf16.h>

#define NNODES 50000
#define NEDGES 1600000
#define ETOT   (NNODES + NEDGES)
#define FIN    256
#define HC     128
#define NEG    0.2f

// ---------------- CSR build (single atomic per edge) ----------------

// rank[i] = arrival order of edge i at its destination; deg[dst] counts.
__global__ void rank_k(const int* __restrict__ ei, int* __restrict__ rank,
                       int* __restrict__ deg, int E) {
    int i = blockIdx.x * blockDim.x + threadIdx.x;
    if (i < E) rank[i] = atomicAdd(&deg[ei[E + i]], 1);
}

// exclusive scan of (deg[i]+1)  — +1 reserves the self-loop slot per node
__global__ void scan_block(const int* __restrict__ deg, int* __restrict__ out,
                           int* __restrict__ bsum, int n) {
    __shared__ int sh[256];
    int t = threadIdx.x;
    int i = blockIdx.x * 256 + t;
    int v = (i < n) ? (deg[i] + 1) : 0;
    sh[t] = v;
    __syncthreads();
    for (int o = 1; o < 256; o <<= 1) {
        int a = (t >= o) ? sh[t - o] : 0;
        __syncthreads();
        sh[t] += a;
        __syncthreads();
    }
    if (i < n) out[i] = sh[t] - v;          // exclusive within block
    if (t == 255) bsum[blockIdx.x] = sh[255];
}

__global__ void scan_top(int* __restrict__ bsum, int nb) {
    __shared__ int sh[256];
    int t = threadIdx.x;
    int v = (t < nb) ? bsum[t] : 0;
    sh[t] = v;
    __syncthreads();
    for (int o = 1; o < 256; o <<= 1) {
        int a = (t >= o) ? sh[t - o] : 0;
        __syncthreads();
        sh[t] += a;
        __syncthreads();
    }
    if (t < nb) bsum[t] = sh[t] - v;        // exclusive
}

__global__ void scan_add(int* __restrict__ rp, const int* __restrict__ boff,
                         int n, int etot) {
    int i = blockIdx.x * blockDim.x + threadIdx.x;
    if (i < n)      rp[i] += boff[i >> 8];
    else if (i == n) rp[n] = etot;
}

// atomic-free scatter: final slot = rp[dst] + rank[i]
__global__ void scatter_k(const int* __restrict__ ei, const float* __restrict__ ea,
                          const int* __restrict__ rp, const int* __restrict__ rank,
                          int* __restrict__ csr_src, float* __restrict__ csr_ea, int E) {
    int i = blockIdx.x * blockDim.x + threadIdx.x;
    if (i < E) {
        int d = ei[E + i];
        int pos = rp[d] + rank[i];
        csr_src[pos] = ei[i];
        csr_ea[pos] = ea[i];
    }
}

// self-loop slot (last in each segment): attr = mean of incoming edge attrs
__global__ __launch_bounds__(256) void selfloop_k(const int* __restrict__ rp,
                                                  int* __restrict__ csr_src,
                                                  float* __restrict__ csr_ea, int n) {
    int wid = (blockIdx.x * blockDim.x + threadIdx.x) >> 6;
    int lane = threadIdx.x & 63;
    if (wid >= n) return;
    int beg = rp[wid], end = rp[wid + 1] - 1;   // [beg,end) = real edges
    float s = 0.f;
    for (int j = beg + lane; j < end; j += 64) s += csr_ea[j];
    for (int o = 32; o; o >>= 1) s += __shfl_xor(s, o, 64);
    if (lane == 0) {
        csr_ea[end] = s / fmaxf((float)(end - beg), 1.0f);
        csr_src[end] = wid;
    }
}

// wedot[h] = sum_c We[h*32+c]*ae[h*32+c]  (layers 1,2: 4 heads; layer 3: scalar)
__global__ void wedot_k(const float* We1, const float* ae1,
                        const float* We2, const float* ae2,
                        const float* We3, const float* ae3,
                        float* __restrict__ wedot) {
    int t = threadIdx.x;  // 128
    float p1 = We1[t] * ae1[t];
    float p2 = We2[t] * ae2[t];
    for (int o = 16; o; o >>= 1) {
        p1 += __shfl_xor(p1, o, 32);
        p2 += __shfl_xor(p2, o, 32);
    }
    if ((t & 31) == 0) {
        wedot[t >> 5] = p1;
        wedot[4 + (t >> 5)] = p2;
    }
    if (t == 0) wedot[8] = We3[0] * ae3[0];
}

// ---------------- GEMM + ls/ld epilogue ----------------
template <int K>
__global__ __launch_bounds__(128) void gemm_lsld(
        const float* __restrict__ x, const float* __restrict__ W,
        const float* __restrict__ a_s, const float* __restrict__ a_d,
        float* __restrict__ h, float* __restrict__ ls, float* __restrict__ ld_,
        int n) {
    const int ROWS = 16;
    __shared__ float xs[ROWS * 32];
    int t = threadIdx.x;  // 128 = output column
    int r0 = blockIdx.x * ROWS;

    float acc[ROWS];
#pragma unroll
    for (int r = 0; r < ROWS; r++) acc[r] = 0.f;

    for (int kc = 0; kc < K; kc += 32) {
        __syncthreads();
#pragma unroll
        for (int q = 0; q < 4; q++) {
            int idx = q * 128 + t;
            int row = idx >> 5, k = idx & 31;
            xs[idx] = (r0 + row < n) ? x[(size_t)(r0 + row) * K + kc + k] : 0.f;
        }
        __syncthreads();
#pragma unroll
        for (int kk = 0; kk < 32; kk++) {
            float w = W[(size_t)(kc + kk) * HC + t];
#pragma unroll
            for (int r = 0; r < ROWS; r++)
                acc[r] = fmaf(xs[r * 32 + kk], w, acc[r]);
        }
    }

    float sa = a_s[t], sd = a_d[t];
#pragma unroll
    for (int r = 0; r < ROWS; r++) {
        int row = r0 + r;
        if (row >= n) break;
        float v = acc[r];
        h[(size_t)row * HC + t] = v;
        float p = v * sa, q = v * sd;
        for (int o = 16; o; o >>= 1) {
            p += __shfl_xor(p, o, 32);
            q += __shfl_xor(q, o, 32);
        }
        if ((t & 31) == 0) {
            ls[row * 4 + (t >> 5)] = p;
            ld_[row * 4 + (t >> 5)] = q;
        }
    }
}

// ---------------- per-node softmax aggregation ----------------
template <bool RELU, bool FUSE3>
__global__ __launch_bounds__(128) void agg_k(
        const float* __restrict__ h, const float* __restrict__ ls,
        const float* __restrict__ ld_, const int* __restrict__ row_ptr,
        const int* __restrict__ csr_src, const float* __restrict__ csr_ea,
        const float* __restrict__ wedot, const float* __restrict__ bias,
        float* __restrict__ out, const float* __restrict__ W3,
        float* __restrict__ h3, int n) {
    int nid = blockIdx.x;
    int t = threadIdx.x, head = t >> 5, lane = t & 31;
    int beg = row_ptr[nid], end = row_ptr[nid + 1];
    float ldn = ld_[nid * 4 + head];
    float wd = wedot[head];

    // pass 1: per-head max (lane-parallel)
    float mx = -1e30f;
    for (int j = beg + lane; j < end; j += 32) {
        int s = csr_src[j];
        float lg = ls[s * 4 + head] + ldn + csr_ea[j] * wd;
        lg = lg > 0.f ? lg : NEG * lg;
        mx = fmaxf(mx, lg);
    }
    for (int o = 16; o; o >>= 1) mx = fmaxf(mx, __shfl_xor(mx, o, 32));

    // pass 2: exp/sum + weighted feature accumulation
    float sum = 0.f, acc = 0.f;
    for (int j = beg; j < end; j++) {
        int s = csr_src[j];
        float lg = ls[s * 4 + head] + ldn + csr_ea[j] * wd;
        lg = lg > 0.f ? lg : NEG * lg;
        float p = __expf(lg - mx);
        sum += p;
        acc = fmaf(p, h[(size_t)s * HC + t], acc);
    }
    float v = acc / (sum + 1e-16f) + bias[t];
    if (RELU) v = fmaxf(v, 0.f);
    out[(size_t)nid * HC + t] = v;

    if (FUSE3) {
        float p = v * W3[t];
        for (int o = 32; o; o >>= 1) p += __shfl_xor(p, o, 64);
        __shared__ float sh[2];
        if ((t & 63) == 0) sh[t >> 6] = p;
        __syncthreads();
        if (t == 0) h3[nid] = sh[0] + sh[1];
    }
}

// ---------------- layer 3 (1 head, 1 channel), wave per node ----------------
__global__ __launch_bounds__(256) void layer3_k(
        const float* __restrict__ h3, const int* __restrict__ row_ptr,
        const int* __restrict__ csr_src, const float* __restrict__ csr_ea,
        const float* __restrict__ wedot, const float* __restrict__ as3,
        const float* __restrict__ ad3, const float* __restrict__ b3,
        float* __restrict__ out, int n) {
    int wid = (blockIdx.x * blockDim.x + threadIdx.x) >> 6;
    int lane = threadIdx.x & 63;
    if (wid >= n) return;
    float A = as3[0], D = ad3[0], wd = wedot[8];
    int beg = row_ptr[wid], end = row_ptr[wid + 1];
    float hdn = h3[wid] * D;

    float mx = -1e30f;
    for (int j = beg + lane; j < end; j += 64) {
        float lg = h3[csr_src[j]] * A + hdn + csr_ea[j] * wd;
        lg = lg > 0.f ? lg : NEG * lg;
        mx = fmaxf(mx, lg);
    }
    for (int o = 32; o; o >>= 1) mx = fmaxf(mx, __shfl_xor(mx, o, 64));

    float sum = 0.f, num = 0.f;
    for (int j = beg + lane; j < end; j += 64) {
        float hv = h3[csr_src[j]];
        float lg = hv * A + hdn + csr_ea[j] * wd;
        lg = lg > 0.f ? lg : NEG * lg;
        float p = __expf(lg - mx);
        sum += p;
        num = fmaf(p, hv, num);
    }
    for (int o = 32; o; o >>= 1) {
        sum += __shfl_xor(sum, o, 64);
        num += __shfl_xor(num, o, 64);
    }
    if (lane == 0) out[wid] = num / (sum + 1e-16f) + b3[0];
}

// ---------------- launch ----------------

extern "C" void kernel_launch(void* const* d_in, const int* in_sizes, int n_in,
                              void* d_out, int out_size, void* d_ws, size_t ws_size,
                              hipStream_t stream) {
    const float* x   = (const float*)d_in[0];
    const int*   ei  = (const int*)d_in[1];
    const float* ea  = (const float*)d_in[2];
    const float* W1  = (const float*)d_in[3];
    const float* We1 = (const float*)d_in[4];
    const float* as1 = (const float*)d_in[5];
    const float* ad1 = (const float*)d_in[6];
    const float* ae1 = (const float*)d_in[7];
    const float* b1  = (const float*)d_in[8];
    const float* W2  = (const float*)d_in[9];
    const float* We2 = (const float*)d_in[10];
    const float* as2 = (const float*)d_in[11];
    const float* ad2 = (const float*)d_in[12];
    const float* ae2 = (const float*)d_in[13];
    const float* b2  = (const float*)d_in[14];
    const float* W3  = (const float*)d_in[15];
    const float* We3 = (const float*)d_in[16];
    const float* as3 = (const float*)d_in[17];
    const float* ad3 = (const float*)d_in[18];
    const float* ae3 = (const float*)d_in[19];
    const float* b3  = (const float*)d_in[20];

    const int N = NNODES, E = NEDGES, etot = ETOT;

    char* ws = (char*)d_ws;
    size_t o = 0;
    auto alloc = [&](size_t bytes) { size_t r = o; o = (o + bytes + 255) & ~(size_t)255; return r; };
    size_t o_deg   = alloc((size_t)N * 4);
    size_t zero_span = o;                       // memset region: deg only
    size_t o_rp    = alloc((size_t)(N + 1) * 4);
    size_t o_bsum  = alloc(256 * 4);
    size_t o_wd    = alloc(16 * 4);
    size_t o_rank  = alloc((size_t)E * 4);
    size_t o_csrs  = alloc((size_t)etot * 4);
    size_t o_csre  = alloc((size_t)etot * 4);
    size_t o_ls    = alloc((size_t)N * 4 * 4);
    size_t o_ld    = alloc((size_t)N * 4 * 4);
    size_t o_h3    = alloc((size_t)N * 4);
    size_t o_bufA  = alloc((size_t)N * HC * 4);
    size_t o_bufB  = alloc((size_t)N * HC * 4);

    int*   deg   = (int*)(ws + o_deg);
    int*   rp    = (int*)(ws + o_rp);
    int*   bsum  = (int*)(ws + o_bsum);
    float* wd    = (float*)(ws + o_wd);
    int*   rank  = (int*)(ws + o_rank);
    int*   csrs  = (int*)(ws + o_csrs);
    float* csre  = (float*)(ws + o_csre);
    float* ls    = (float*)(ws + o_ls);
    float* ld_   = (float*)(ws + o_ld);
    float* h3    = (float*)(ws + o_h3);
    float* bufA  = (float*)(ws + o_bufA);
    float* bufB  = (float*)(ws + o_bufB);

    hipMemsetAsync(ws, 0, zero_span, stream);

    int nb = (N + 255) / 256;
    rank_k<<<(E + 255) / 256, 256, 0, stream>>>(ei, rank, deg, E);
    scan_block<<<nb, 256, 0, stream>>>(deg, rp, bsum, N);
    scan_top<<<1, 256, 0, stream>>>(bsum, nb);
    scan_add<<<(N + 256) / 256, 256, 0, stream>>>(rp, bsum, N, etot);
    scatter_k<<<(E + 255) / 256, 256, 0, stream>>>(ei, ea, rp, rank, csrs, csre, E);
    selfloop_k<<<(N * 64 + 255) / 256, 256, 0, stream>>>(rp, csrs, csre, N);
    wedot_k<<<1, 128, 0, stream>>>(We1, ae1, We2, ae2, We3, ae3, wd);

    // layer 1
    gemm_lsld<FIN><<<(N + 15) / 16, 128, 0, stream>>>(x, W1, as1, ad1, bufA, ls, ld_, N);
    agg_k<true, false><<<N, 128, 0, stream>>>(bufA, ls, ld_, rp, csrs, csre, wd, b1,
                                              bufB, nullptr, nullptr, N);
    // layer 2 (+ fused layer-3 projection)
    gemm_lsld<HC><<<(N + 15) / 16, 128, 0, stream>>>(bufB, W2, as2, ad2, bufA, ls, ld_, N);
    agg_k<true, true><<<N, 128, 0, stream>>>(bufA, ls, ld_, rp, csrs, csre, wd + 4, b2,
                                             bufB, W3, h3, N);
    // layer 3
    layer3_k<<<(N * 64 + 255) / 256, 256, 0, stream>>>(h3, rp, csrs, csre, wd, as3, ad3, b3,
                                                       (float*)d_out, N);
}

// Round 3
// 606.587 us; speedup vs baseline: 1.6442x; 1.2604x over previous
//
#include <hip/hip_runtime.h>
#include <hip/hip_bf16.h>

#define NNODES 50000
#define NEDGES 1600000
#define ETOT   (NNODES + NEDGES)
#define FIN    256
#define HC     128
#define NEG    0.2f
#define DEGCAP 128

// ---------------- CSR build (single atomic per edge) ----------------

__global__ void rank_k(const int* __restrict__ ei, int* __restrict__ rank,
                       int* __restrict__ deg, int E) {
    int i = blockIdx.x * blockDim.x + threadIdx.x;
    if (i < E) rank[i] = atomicAdd(&deg[ei[E + i]], 1);
}

// exclusive scan of (deg[i]+1)  — +1 reserves the self-loop slot per node
__global__ void scan_block(const int* __restrict__ deg, int* __restrict__ out,
                           int* __restrict__ bsum, int n) {
    __shared__ int sh[256];
    int t = threadIdx.x;
    int i = blockIdx.x * 256 + t;
    int v = (i < n) ? (deg[i] + 1) : 0;
    sh[t] = v;
    __syncthreads();
    for (int o = 1; o < 256; o <<= 1) {
        int a = (t >= o) ? sh[t - o] : 0;
        __syncthreads();
        sh[t] += a;
        __syncthreads();
    }
    if (i < n) out[i] = sh[t] - v;
    if (t == 255) bsum[blockIdx.x] = sh[255];
}

__global__ void scan_top(int* __restrict__ bsum, int nb) {
    __shared__ int sh[256];
    int t = threadIdx.x;
    int v = (t < nb) ? bsum[t] : 0;
    sh[t] = v;
    __syncthreads();
    for (int o = 1; o < 256; o <<= 1) {
        int a = (t >= o) ? sh[t - o] : 0;
        __syncthreads();
        sh[t] += a;
        __syncthreads();
    }
    if (t < nb) bsum[t] = sh[t] - v;
}

__global__ void scan_add(int* __restrict__ rp, const int* __restrict__ boff,
                         int n, int etot) {
    int i = blockIdx.x * blockDim.x + threadIdx.x;
    if (i < n)      rp[i] += boff[i >> 8];
    else if (i == n) rp[n] = etot;
}

__global__ void scatter_k(const int* __restrict__ ei, const float* __restrict__ ea,
                          const int* __restrict__ rp, const int* __restrict__ rank,
                          int* __restrict__ csr_src, float* __restrict__ csr_ea, int E) {
    int i = blockIdx.x * blockDim.x + threadIdx.x;
    if (i < E) {
        int d = ei[E + i];
        int pos = rp[d] + rank[i];
        csr_src[pos] = ei[i];
        csr_ea[pos] = ea[i];
    }
}

__global__ __launch_bounds__(256) void selfloop_k(const int* __restrict__ rp,
                                                  int* __restrict__ csr_src,
                                                  float* __restrict__ csr_ea, int n) {
    int wid = (blockIdx.x * blockDim.x + threadIdx.x) >> 6;
    int lane = threadIdx.x & 63;
    if (wid >= n) return;
    int beg = rp[wid], end = rp[wid + 1] - 1;
    float s = 0.f;
    for (int j = beg + lane; j < end; j += 64) s += csr_ea[j];
    for (int o = 32; o; o >>= 1) s += __shfl_xor(s, o, 64);
    if (lane == 0) {
        csr_ea[end] = s / fmaxf((float)(end - beg), 1.0f);
        csr_src[end] = wid;
    }
}

__global__ void wedot_k(const float* We1, const float* ae1,
                        const float* We2, const float* ae2,
                        const float* We3, const float* ae3,
                        float* __restrict__ wedot) {
    int t = threadIdx.x;
    float p1 = We1[t] * ae1[t];
    float p2 = We2[t] * ae2[t];
    for (int o = 16; o; o >>= 1) {
        p1 += __shfl_xor(p1, o, 32);
        p2 += __shfl_xor(p2, o, 32);
    }
    if ((t & 31) == 0) {
        wedot[t >> 5] = p1;
        wedot[4 + (t >> 5)] = p2;
    }
    if (t == 0) wedot[8] = We3[0] * ae3[0];
}

// ---------------- GEMM + ls/ld epilogue ----------------
template <int K>
__global__ __launch_bounds__(128) void gemm_lsld(
        const float* __restrict__ x, const float* __restrict__ W,
        const float* __restrict__ a_s, const float* __restrict__ a_d,
        float* __restrict__ h, float* __restrict__ ls, float* __restrict__ ld_,
        int n) {
    const int ROWS = 16;
    __shared__ float xs[ROWS * 32];
    int t = threadIdx.x;
    int r0 = blockIdx.x * ROWS;

    float acc[ROWS];
#pragma unroll
    for (int r = 0; r < ROWS; r++) acc[r] = 0.f;

    for (int kc = 0; kc < K; kc += 32) {
        __syncthreads();
#pragma unroll
        for (int q = 0; q < 4; q++) {
            int idx = q * 128 + t;
            int row = idx >> 5, k = idx & 31;
            xs[idx] = (r0 + row < n) ? x[(size_t)(r0 + row) * K + kc + k] : 0.f;
        }
        __syncthreads();
#pragma unroll
        for (int kk = 0; kk < 32; kk++) {
            float w = W[(size_t)(kc + kk) * HC + t];
#pragma unroll
            for (int r = 0; r < ROWS; r++)
                acc[r] = fmaf(xs[r * 32 + kk], w, acc[r]);
        }
    }

    float sa = a_s[t], sd = a_d[t];
#pragma unroll
    for (int r = 0; r < ROWS; r++) {
        int row = r0 + r;
        if (row >= n) break;
        float v = acc[r];
        h[(size_t)row * HC + t] = v;
        float p = v * sa, q = v * sd;
        for (int o = 16; o; o >>= 1) {
            p += __shfl_xor(p, o, 32);
            q += __shfl_xor(q, o, 32);
        }
        if ((t & 31) == 0) {
            ls[row * 4 + (t >> 5)] = p;
            ld_[row * 4 + (t >> 5)] = q;
        }
    }
}

// ---------------- per-node softmax aggregation (LDS-staged alpha) ----------------
template <bool RELU, bool FUSE3>
__global__ __launch_bounds__(128) void agg_k(
        const float* __restrict__ h, const float* __restrict__ ls,
        const float* __restrict__ ld_, const int* __restrict__ row_ptr,
        const int* __restrict__ csr_src, const float* __restrict__ csr_ea,
        const float* __restrict__ wedot, const float* __restrict__ bias,
        float* __restrict__ out, const float* __restrict__ W3,
        float* __restrict__ h3, int n) {
    __shared__ float albuf[4][DEGCAP];
    __shared__ int srcbuf[DEGCAP];
    int nid = blockIdx.x;
    int t = threadIdx.x, head = t >> 5, lane = t & 31;
    int beg = row_ptr[nid], end = row_ptr[nid + 1];
    int deg = end - beg;
    float ldn = ld_[nid * 4 + head];
    float wd = wedot[head];

    float v;
    if (deg <= DEGCAP) {
        // pass 1: logits once per (edge, head) -> LDS; head-0 group caches src ids
        float mx = -1e30f;
        for (int e = lane; e < deg; e += 32) {
            int s = csr_src[beg + e];
            if (head == 0) srcbuf[e] = s;
            float lg = ls[s * 4 + head] + ldn + csr_ea[beg + e] * wd;
            lg = lg > 0.f ? lg : NEG * lg;
            albuf[head][e] = lg;
            mx = fmaxf(mx, lg);
        }
        for (int o = 16; o; o >>= 1) mx = fmaxf(mx, __shfl_xor(mx, o, 32));

        // pass 2: exp + sum from LDS (no re-gather)
        float sum = 0.f;
        for (int e = lane; e < deg; e += 32) {
            float p = __expf(albuf[head][e] - mx);
            albuf[head][e] = p;
            sum += p;
        }
        for (int o = 16; o; o >>= 1) sum += __shfl_xor(sum, o, 32);
        __syncthreads();   // srcbuf visible to both waves

        // pass 3: h gather, 4-wide unroll for memory concurrency
        float acc = 0.f;
        int e = 0;
        for (; e + 4 <= deg; e += 4) {
            int s0 = srcbuf[e], s1 = srcbuf[e + 1], s2 = srcbuf[e + 2], s3 = srcbuf[e + 3];
            float h0 = h[(size_t)s0 * HC + t];
            float h1 = h[(size_t)s1 * HC + t];
            float h2 = h[(size_t)s2 * HC + t];
            float h3v = h[(size_t)s3 * HC + t];
            float a0 = albuf[head][e], a1 = albuf[head][e + 1];
            float a2 = albuf[head][e + 2], a3 = albuf[head][e + 3];
            acc = fmaf(a0, h0, acc);
            acc = fmaf(a1, h1, acc);
            acc = fmaf(a2, h2, acc);
            acc = fmaf(a3, h3v, acc);
        }
        for (; e < deg; e++)
            acc = fmaf(albuf[head][e], h[(size_t)srcbuf[e] * HC + t], acc);
        v = acc / (sum + 1e-16f) + bias[t];
    } else {
        // fallback: recompute path (never hit for Poisson(32) degrees, kept for safety)
        float mx = -1e30f;
        for (int j = beg + lane; j < end; j += 32) {
            int s = csr_src[j];
            float lg = ls[s * 4 + head] + ldn + csr_ea[j] * wd;
            lg = lg > 0.f ? lg : NEG * lg;
            mx = fmaxf(mx, lg);
        }
        for (int o = 16; o; o >>= 1) mx = fmaxf(mx, __shfl_xor(mx, o, 32));
        float sum = 0.f, acc = 0.f;
        for (int j = beg; j < end; j++) {
            int s = csr_src[j];
            float lg = ls[s * 4 + head] + ldn + csr_ea[j] * wd;
            lg = lg > 0.f ? lg : NEG * lg;
            float p = __expf(lg - mx);
            sum += p;
            acc = fmaf(p, h[(size_t)s * HC + t], acc);
        }
        v = acc / (sum + 1e-16f) + bias[t];
        __syncthreads();   // match fast path's barrier count
    }

    if (RELU) v = fmaxf(v, 0.f);
    out[(size_t)nid * HC + t] = v;

    if (FUSE3) {
        float p = v * W3[t];
        for (int o = 32; o; o >>= 1) p += __shfl_xor(p, o, 64);
        __shared__ float sh[2];
        if ((t & 63) == 0) sh[t >> 6] = p;
        __syncthreads();
        if (t == 0) h3[nid] = sh[0] + sh[1];
    }
}

// ---------------- layer 3 (1 head, 1 channel), wave per node ----------------
__global__ __launch_bounds__(256) void layer3_k(
        const float* __restrict__ h3, const int* __restrict__ row_ptr,
        const int* __restrict__ csr_src, const float* __restrict__ csr_ea,
        const float* __restrict__ wedot, const float* __restrict__ as3,
        const float* __restrict__ ad3, const float* __restrict__ b3,
        float* __restrict__ out, int n) {
    int wid = (blockIdx.x * blockDim.x + threadIdx.x) >> 6;
    int lane = threadIdx.x & 63;
    if (wid >= n) return;
    float A = as3[0], D = ad3[0], wd = wedot[8];
    int beg = row_ptr[wid], end = row_ptr[wid + 1];
    float hdn = h3[wid] * D;

    float mx = -1e30f;
    for (int j = beg + lane; j < end; j += 64) {
        float lg = h3[csr_src[j]] * A + hdn + csr_ea[j] * wd;
        lg = lg > 0.f ? lg : NEG * lg;
        mx = fmaxf(mx, lg);
    }
    for (int o = 32; o; o >>= 1) mx = fmaxf(mx, __shfl_xor(mx, o, 64));

    float sum = 0.f, num = 0.f;
    for (int j = beg + lane; j < end; j += 64) {
        float hv = h3[csr_src[j]];
        float lg = hv * A + hdn + csr_ea[j] * wd;
        lg = lg > 0.f ? lg : NEG * lg;
        float p = __expf(lg - mx);
        sum += p;
        num = fmaf(p, hv, num);
    }
    for (int o = 32; o; o >>= 1) {
        sum += __shfl_xor(sum, o, 64);
        num += __shfl_xor(num, o, 64);
    }
    if (lane == 0) out[wid] = num / (sum + 1e-16f) + b3[0];
}

// ---------------- launch ----------------

extern "C" void kernel_launch(void* const* d_in, const int* in_sizes, int n_in,
                              void* d_out, int out_size, void* d_ws, size_t ws_size,
                              hipStream_t stream) {
    const float* x   = (const float*)d_in[0];
    const int*   ei  = (const int*)d_in[1];
    const float* ea  = (const float*)d_in[2];
    const float* W1  = (const float*)d_in[3];
    const float* We1 = (const float*)d_in[4];
    const float* as1 = (const float*)d_in[5];
    const float* ad1 = (const float*)d_in[6];
    const float* ae1 = (const float*)d_in[7];
    const float* b1  = (const float*)d_in[8];
    const float* W2  = (const float*)d_in[9];
    const float* We2 = (const float*)d_in[10];
    const float* as2 = (const float*)d_in[11];
    const float* ad2 = (const float*)d_in[12];
    const float* ae2 = (const float*)d_in[13];
    const float* b2  = (const float*)d_in[14];
    const float* W3  = (const float*)d_in[15];
    const float* We3 = (const float*)d_in[16];
    const float* as3 = (const float*)d_in[17];
    const float* ad3 = (const float*)d_in[18];
    const float* ae3 = (const float*)d_in[19];
    const float* b3  = (const float*)d_in[20];

    const int N = NNODES, E = NEDGES, etot = ETOT;

    char* ws = (char*)d_ws;
    size_t o = 0;
    auto alloc = [&](size_t bytes) { size_t r = o; o = (o + bytes + 255) & ~(size_t)255; return r; };
    size_t o_deg   = alloc((size_t)N * 4);
    size_t zero_span = o;
    size_t o_rp    = alloc((size_t)(N + 1) * 4);
    size_t o_bsum  = alloc(256 * 4);
    size_t o_wd    = alloc(16 * 4);
    size_t o_rank  = alloc((size_t)E * 4);
    size_t o_csrs  = alloc((size_t)etot * 4);
    size_t o_csre  = alloc((size_t)etot * 4);
    size_t o_ls    = alloc((size_t)N * 4 * 4);
    size_t o_ld    = alloc((size_t)N * 4 * 4);
    size_t o_h3    = alloc((size_t)N * 4);
    size_t o_bufA  = alloc((size_t)N * HC * 4);
    size_t o_bufB  = alloc((size_t)N * HC * 4);

    int*   deg   = (int*)(ws + o_deg);
    int*   rp    = (int*)(ws + o_rp);
    int*   bsum  = (int*)(ws + o_bsum);
    float* wd    = (float*)(ws + o_wd);
    int*   rank  = (int*)(ws + o_rank);
    int*   csrs  = (int*)(ws + o_csrs);
    float* csre  = (float*)(ws + o_csre);
    float* ls    = (float*)(ws + o_ls);
    float* ld_   = (float*)(ws + o_ld);
    float* h3    = (float*)(ws + o_h3);
    float* bufA  = (float*)(ws + o_bufA);
    float* bufB  = (float*)(ws + o_bufB);

    hipMemsetAsync(ws, 0, zero_span, stream);

    int nb = (N + 255) / 256;
    rank_k<<<(E + 255) / 256, 256, 0, stream>>>(ei, rank, deg, E);
    scan_block<<<nb, 256, 0, stream>>>(deg, rp, bsum, N);
    scan_top<<<1, 256, 0, stream>>>(bsum, nb);
    scan_add<<<(N + 256) / 256, 256, 0, stream>>>(rp, bsum, N, etot);
    scatter_k<<<(E + 255) / 256, 256, 0, stream>>>(ei, ea, rp, rank, csrs, csre, E);
    selfloop_k<<<(N * 64 + 255) / 256, 256, 0, stream>>>(rp, csrs, csre, N);
    wedot_k<<<1, 128, 0, stream>>>(We1, ae1, We2, ae2, We3, ae3, wd);

    // layer 1
    gemm_lsld<FIN><<<(N + 15) / 16, 128, 0, stream>>>(x, W1, as1, ad1, bufA, ls, ld_, N);
    agg_k<true, false><<<N, 128, 0, stream>>>(bufA, ls, ld_, rp, csrs, csre, wd, b1,
                                              bufB, nullptr, nullptr, N);
    // layer 2 (+ fused layer-3 projection)
    gemm_lsld<HC><<<(N + 15) / 16, 128, 0, stream>>>(bufB, W2, as2, ad2, bufA, ls, ld_, N);
    agg_k<true, true><<<N, 128, 0, stream>>>(bufA, ls, ld_, rp, csrs, csre, wd + 4, b2,
                                             bufB, W3, h3, N);
    // layer 3
    layer3_k<<<(N * 64 + 255) / 256, 256, 0, stream>>>(h3, rp, csrs, csre, wd, as3, ad3, b3,
                                                       (float*)d_out, N);
}

// Round 4
// 485.049 us; speedup vs baseline: 2.0562x; 1.2506x over previous
//
#include <hip/hip_runtime.h>
#include <hip/hip_bf16.h>

#define NNODES 50000
#define NEDGES 1600000
#define ETOT   (NNODES + NEDGES)
#define FIN    256
#define HC     128
#define NEG    0.2f
#define DEGCAP 128

// ---------------- CSR build (single atomic per edge) ----------------

__global__ void rank_k(const int* __restrict__ ei, int* __restrict__ rank,
                       int* __restrict__ deg, int E) {
    int i = blockIdx.x * blockDim.x + threadIdx.x;
    if (i < E) rank[i] = atomicAdd(&deg[ei[E + i]], 1);
}

// exclusive scan of (deg[i]+1)  — +1 reserves the self-loop slot per node
__global__ void scan_block(const int* __restrict__ deg, int* __restrict__ out,
                           int* __restrict__ bsum, int n) {
    __shared__ int sh[256];
    int t = threadIdx.x;
    int i = blockIdx.x * 256 + t;
    int v = (i < n) ? (deg[i] + 1) : 0;
    sh[t] = v;
    __syncthreads();
    for (int o = 1; o < 256; o <<= 1) {
        int a = (t >= o) ? sh[t - o] : 0;
        __syncthreads();
        sh[t] += a;
        __syncthreads();
    }
    if (i < n) out[i] = sh[t] - v;
    if (t == 255) bsum[blockIdx.x] = sh[255];
}

__global__ void scan_top(int* __restrict__ bsum, int nb) {
    __shared__ int sh[256];
    int t = threadIdx.x;
    int v = (t < nb) ? bsum[t] : 0;
    sh[t] = v;
    __syncthreads();
    for (int o = 1; o < 256; o <<= 1) {
        int a = (t >= o) ? sh[t - o] : 0;
        __syncthreads();
        sh[t] += a;
        __syncthreads();
    }
    if (t < nb) bsum[t] = sh[t] - v;
}

__global__ void scan_add(int* __restrict__ rp, const int* __restrict__ boff,
                         int n, int etot) {
    int i = blockIdx.x * blockDim.x + threadIdx.x;
    if (i < n)      rp[i] += boff[i >> 8];
    else if (i == n) rp[n] = etot;
}

__global__ void scatter_k(const int* __restrict__ ei, const float* __restrict__ ea,
                          const int* __restrict__ rp, const int* __restrict__ rank,
                          int* __restrict__ csr_src, float* __restrict__ csr_ea, int E) {
    int i = blockIdx.x * blockDim.x + threadIdx.x;
    if (i < E) {
        int d = ei[E + i];
        int pos = rp[d] + rank[i];
        csr_src[pos] = ei[i];
        csr_ea[pos] = ea[i];
    }
}

__global__ __launch_bounds__(256) void selfloop_k(const int* __restrict__ rp,
                                                  int* __restrict__ csr_src,
                                                  float* __restrict__ csr_ea, int n) {
    int wid = (blockIdx.x * blockDim.x + threadIdx.x) >> 6;
    int lane = threadIdx.x & 63;
    if (wid >= n) return;
    int beg = rp[wid], end = rp[wid + 1] - 1;
    float s = 0.f;
    for (int j = beg + lane; j < end; j += 64) s += csr_ea[j];
    for (int o = 32; o; o >>= 1) s += __shfl_xor(s, o, 64);
    if (lane == 0) {
        csr_ea[end] = s / fmaxf((float)(end - beg), 1.0f);
        csr_src[end] = wid;
    }
}

__global__ void wedot_k(const float* We1, const float* ae1,
                        const float* We2, const float* ae2,
                        const float* We3, const float* ae3,
                        float* __restrict__ wedot) {
    int t = threadIdx.x;
    float p1 = We1[t] * ae1[t];
    float p2 = We2[t] * ae2[t];
    for (int o = 16; o; o >>= 1) {
        p1 += __shfl_xor(p1, o, 32);
        p2 += __shfl_xor(p2, o, 32);
    }
    if ((t & 31) == 0) {
        wedot[t >> 5] = p1;
        wedot[4 + (t >> 5)] = p2;
    }
    if (t == 0) wedot[8] = We3[0] * ae3[0];
}

// ---------------- register-blocked GEMM + ls/ld epilogue ----------------
// 256 threads, tile 64x128, thread = 8 rows x 4 cols. A-tile transposed+swizzled.
template <int K>
__global__ __launch_bounds__(256) void gemm_lsld(
        const float* __restrict__ x, const float* __restrict__ W,
        const float* __restrict__ a_s, const float* __restrict__ a_d,
        float* __restrict__ h, float* __restrict__ ls, float* __restrict__ ld_,
        int n) {
    constexpr int BM = 64, BK = 32;
    __shared__ float xsT[BK][BM];   // element (k,m) stored at xsT[k][m ^ ((k&7)<<2)]
    __shared__ float ws[BK][HC];
    int t = threadIdx.x;
    int tx = t & 31;          // cols 4*tx .. 4*tx+3
    int ty = t >> 5;          // rows 8*ty .. 8*ty+7
    int r0 = blockIdx.x * BM;

    float acc[8][4];
#pragma unroll
    for (int r = 0; r < 8; r++)
#pragma unroll
        for (int c = 0; c < 4; c++) acc[r][c] = 0.f;

    for (int kc = 0; kc < K; kc += BK) {
        __syncthreads();
        // stage x tile (64 rows x 32 k), transposed with XOR swizzle
#pragma unroll
        for (int q = 0; q < 2; q++) {
            int idx = q * 256 + t;
            int m = idx >> 3;             // 0..63
            int k4 = (idx & 7) * 4;       // 0,4,..,28
            int row = r0 + m;
            float4 v = (row < n) ? *(const float4*)&x[(size_t)row * K + kc + k4]
                                 : make_float4(0.f, 0.f, 0.f, 0.f);
            float vv[4] = {v.x, v.y, v.z, v.w};
#pragma unroll
            for (int j = 0; j < 4; j++) {
                int k = k4 + j;
                xsT[k][m ^ ((k & 7) << 2)] = vv[j];
            }
        }
        // stage W tile (32 k x 128 n)
#pragma unroll
        for (int q = 0; q < 4; q++) {
            int idx = q * 256 + t;
            int k = idx >> 5;
            int n4 = (idx & 31) * 4;
            *(float4*)&ws[k][n4] = *(const float4*)&W[(size_t)(kc + k) * HC + n4];
        }
        __syncthreads();
#pragma unroll
        for (int kk = 0; kk < BK; kk++) {
            int s = (kk & 7) << 2;
            float4 a0 = *(const float4*)&xsT[kk][(8 * ty) ^ s];
            float4 a1 = *(const float4*)&xsT[kk][(8 * ty + 4) ^ s];
            float4 w0 = *(const float4*)&ws[kk][4 * tx];
            float a[8] = {a0.x, a0.y, a0.z, a0.w, a1.x, a1.y, a1.z, a1.w};
            float wv[4] = {w0.x, w0.y, w0.z, w0.w};
#pragma unroll
            for (int r = 0; r < 8; r++)
#pragma unroll
                for (int c = 0; c < 4; c++)
                    acc[r][c] = fmaf(a[r], wv[c], acc[r][c]);
        }
    }

    // epilogue: h store + ls/ld via 8-lane reduction (cols of one head)
    int head = tx >> 3;
    float4 sa4 = *(const float4*)&a_s[4 * tx];
    float4 sd4 = *(const float4*)&a_d[4 * tx];
    float sa[4] = {sa4.x, sa4.y, sa4.z, sa4.w};
    float sd[4] = {sd4.x, sd4.y, sd4.z, sd4.w};
#pragma unroll
    for (int r = 0; r < 8; r++) {
        int row = r0 + 8 * ty + r;
        if (row >= n) break;
        float4 o = make_float4(acc[r][0], acc[r][1], acc[r][2], acc[r][3]);
        *(float4*)&h[(size_t)row * HC + 4 * tx] = o;
        float p = acc[r][0] * sa[0] + acc[r][1] * sa[1] + acc[r][2] * sa[2] + acc[r][3] * sa[3];
        float q = acc[r][0] * sd[0] + acc[r][1] * sd[1] + acc[r][2] * sd[2] + acc[r][3] * sd[3];
        p += __shfl_xor(p, 1); q += __shfl_xor(q, 1);
        p += __shfl_xor(p, 2); q += __shfl_xor(q, 2);
        p += __shfl_xor(p, 4); q += __shfl_xor(q, 4);
        if ((tx & 7) == 0) {
            ls[row * 4 + head] = p;
            ld_[row * 4 + head] = q;
        }
    }
}

// ---------------- per-node softmax aggregation (LDS-staged alpha) ----------------
template <bool RELU, bool FUSE3>
__global__ __launch_bounds__(128) void agg_k(
        const float* __restrict__ h, const float* __restrict__ ls,
        const float* __restrict__ ld_, const int* __restrict__ row_ptr,
        const int* __restrict__ csr_src, const float* __restrict__ csr_ea,
        const float* __restrict__ wedot, const float* __restrict__ bias,
        float* __restrict__ out, const float* __restrict__ W3,
        float* __restrict__ h3, int n) {
    __shared__ float albuf[4][DEGCAP];
    __shared__ int srcbuf[DEGCAP];
    int nid = blockIdx.x;
    int t = threadIdx.x, head = t >> 5, lane = t & 31;
    int beg = row_ptr[nid], end = row_ptr[nid + 1];
    int deg = end - beg;
    float ldn = ld_[nid * 4 + head];
    float wd = wedot[head];

    float v;
    if (deg <= DEGCAP) {
        float mx = -1e30f;
        for (int e = lane; e < deg; e += 32) {
            int s = csr_src[beg + e];
            if (head == 0) srcbuf[e] = s;
            float lg = ls[s * 4 + head] + ldn + csr_ea[beg + e] * wd;
            lg = lg > 0.f ? lg : NEG * lg;
            albuf[head][e] = lg;
            mx = fmaxf(mx, lg);
        }
        for (int o = 16; o; o >>= 1) mx = fmaxf(mx, __shfl_xor(mx, o, 32));

        float sum = 0.f;
        for (int e = lane; e < deg; e += 32) {
            float p = __expf(albuf[head][e] - mx);
            albuf[head][e] = p;
            sum += p;
        }
        for (int o = 16; o; o >>= 1) sum += __shfl_xor(sum, o, 32);
        __syncthreads();

        float acc = 0.f;
        int e = 0;
        for (; e + 4 <= deg; e += 4) {
            int s0 = srcbuf[e], s1 = srcbuf[e + 1], s2 = srcbuf[e + 2], s3 = srcbuf[e + 3];
            float h0 = h[(size_t)s0 * HC + t];
            float h1 = h[(size_t)s1 * HC + t];
            float h2 = h[(size_t)s2 * HC + t];
            float h3v = h[(size_t)s3 * HC + t];
            float a0 = albuf[head][e], a1 = albuf[head][e + 1];
            float a2 = albuf[head][e + 2], a3 = albuf[head][e + 3];
            acc = fmaf(a0, h0, acc);
            acc = fmaf(a1, h1, acc);
            acc = fmaf(a2, h2, acc);
            acc = fmaf(a3, h3v, acc);
        }
        for (; e < deg; e++)
            acc = fmaf(albuf[head][e], h[(size_t)srcbuf[e] * HC + t], acc);
        v = acc / (sum + 1e-16f) + bias[t];
    } else {
        float mx = -1e30f;
        for (int j = beg + lane; j < end; j += 32) {
            int s = csr_src[j];
            float lg = ls[s * 4 + head] + ldn + csr_ea[j] * wd;
            lg = lg > 0.f ? lg : NEG * lg;
            mx = fmaxf(mx, lg);
        }
        for (int o = 16; o; o >>= 1) mx = fmaxf(mx, __shfl_xor(mx, o, 32));
        float sum = 0.f, acc = 0.f;
        for (int j = beg; j < end; j++) {
            int s = csr_src[j];
            float lg = ls[s * 4 + head] + ldn + csr_ea[j] * wd;
            lg = lg > 0.f ? lg : NEG * lg;
            float p = __expf(lg - mx);
            sum += p;
            acc = fmaf(p, h[(size_t)s * HC + t], acc);
        }
        v = acc / (sum + 1e-16f) + bias[t];
        __syncthreads();
    }

    if (RELU) v = fmaxf(v, 0.f);
    out[(size_t)nid * HC + t] = v;

    if (FUSE3) {
        float p = v * W3[t];
        for (int o = 32; o; o >>= 1) p += __shfl_xor(p, o, 64);
        __shared__ float sh[2];
        if ((t & 63) == 0) sh[t >> 6] = p;
        __syncthreads();
        if (t == 0) h3[nid] = sh[0] + sh[1];
    }
}

// ---------------- layer 3 (1 head, 1 channel), wave per node ----------------
__global__ __launch_bounds__(256) void layer3_k(
        const float* __restrict__ h3, const int* __restrict__ row_ptr,
        const int* __restrict__ csr_src, const float* __restrict__ csr_ea,
        const float* __restrict__ wedot, const float* __restrict__ as3,
        const float* __restrict__ ad3, const float* __restrict__ b3,
        float* __restrict__ out, int n) {
    int wid = (blockIdx.x * blockDim.x + threadIdx.x) >> 6;
    int lane = threadIdx.x & 63;
    if (wid >= n) return;
    float A = as3[0], D = ad3[0], wd = wedot[8];
    int beg = row_ptr[wid], end = row_ptr[wid + 1];
    float hdn = h3[wid] * D;

    float mx = -1e30f;
    for (int j = beg + lane; j < end; j += 64) {
        float lg = h3[csr_src[j]] * A + hdn + csr_ea[j] * wd;
        lg = lg > 0.f ? lg : NEG * lg;
        mx = fmaxf(mx, lg);
    }
    for (int o = 32; o; o >>= 1) mx = fmaxf(mx, __shfl_xor(mx, o, 64));

    float sum = 0.f, num = 0.f;
    for (int j = beg + lane; j < end; j += 64) {
        float hv = h3[csr_src[j]];
        float lg = hv * A + hdn + csr_ea[j] * wd;
        lg = lg > 0.f ? lg : NEG * lg;
        float p = __expf(lg - mx);
        sum += p;
        num = fmaf(p, hv, num);
    }
    for (int o = 32; o; o >>= 1) {
        sum += __shfl_xor(sum, o, 64);
        num += __shfl_xor(num, o, 64);
    }
    if (lane == 0) out[wid] = num / (sum + 1e-16f) + b3[0];
}

// ---------------- launch ----------------

extern "C" void kernel_launch(void* const* d_in, const int* in_sizes, int n_in,
                              void* d_out, int out_size, void* d_ws, size_t ws_size,
                              hipStream_t stream) {
    const float* x   = (const float*)d_in[0];
    const int*   ei  = (const int*)d_in[1];
    const float* ea  = (const float*)d_in[2];
    const float* W1  = (const float*)d_in[3];
    const float* We1 = (const float*)d_in[4];
    const float* as1 = (const float*)d_in[5];
    const float* ad1 = (const float*)d_in[6];
    const float* ae1 = (const float*)d_in[7];
    const float* b1  = (const float*)d_in[8];
    const float* W2  = (const float*)d_in[9];
    const float* We2 = (const float*)d_in[10];
    const float* as2 = (const float*)d_in[11];
    const float* ad2 = (const float*)d_in[12];
    const float* ae2 = (const float*)d_in[13];
    const float* b2  = (const float*)d_in[14];
    const float* W3  = (const float*)d_in[15];
    const float* We3 = (const float*)d_in[16];
    const float* as3 = (const float*)d_in[17];
    const float* ad3 = (const float*)d_in[18];
    const float* ae3 = (const float*)d_in[19];
    const float* b3  = (const float*)d_in[20];

    const int N = NNODES, E = NEDGES, etot = ETOT;

    char* ws = (char*)d_ws;
    size_t o = 0;
    auto alloc = [&](size_t bytes) { size_t r = o; o = (o + bytes + 255) & ~(size_t)255; return r; };
    size_t o_deg   = alloc((size_t)N * 4);
    size_t zero_span = o;
    size_t o_rp    = alloc((size_t)(N + 1) * 4);
    size_t o_bsum  = alloc(256 * 4);
    size_t o_wd    = alloc(16 * 4);
    size_t o_rank  = alloc((size_t)E * 4);
    size_t o_csrs  = alloc((size_t)etot * 4);
    size_t o_csre  = alloc((size_t)etot * 4);
    size_t o_ls    = alloc((size_t)N * 4 * 4);
    size_t o_ld    = alloc((size_t)N * 4 * 4);
    size_t o_h3    = alloc((size_t)N * 4);
    size_t o_bufA  = alloc((size_t)N * HC * 4);
    size_t o_bufB  = alloc((size_t)N * HC * 4);

    int*   deg   = (int*)(ws + o_deg);
    int*   rp    = (int*)(ws + o_rp);
    int*   bsum  = (int*)(ws + o_bsum);
    float* wd    = (float*)(ws + o_wd);
    int*   rank  = (int*)(ws + o_rank);
    int*   csrs  = (int*)(ws + o_csrs);
    float* csre  = (float*)(ws + o_csre);
    float* ls    = (float*)(ws + o_ls);
    float* ld_   = (float*)(ws + o_ld);
    float* h3    = (float*)(ws + o_h3);
    float* bufA  = (float*)(ws + o_bufA);
    float* bufB  = (float*)(ws + o_bufB);

    hipMemsetAsync(ws, 0, zero_span, stream);

    int nb = (N + 255) / 256;
    rank_k<<<(E + 255) / 256, 256, 0, stream>>>(ei, rank, deg, E);
    scan_block<<<nb, 256, 0, stream>>>(deg, rp, bsum, N);
    scan_top<<<1, 256, 0, stream>>>(bsum, nb);
    scan_add<<<(N + 256) / 256, 256, 0, stream>>>(rp, bsum, N, etot);
    scatter_k<<<(E + 255) / 256, 256, 0, stream>>>(ei, ea, rp, rank, csrs, csre, E);
    selfloop_k<<<(N * 64 + 255) / 256, 256, 0, stream>>>(rp, csrs, csre, N);
    wedot_k<<<1, 128, 0, stream>>>(We1, ae1, We2, ae2, We3, ae3, wd);

    // layer 1
    gemm_lsld<FIN><<<(N + 63) / 64, 256, 0, stream>>>(x, W1, as1, ad1, bufA, ls, ld_, N);
    agg_k<true, false><<<N, 128, 0, stream>>>(bufA, ls, ld_, rp, csrs, csre, wd, b1,
                                              bufB, nullptr, nullptr, N);
    // layer 2 (+ fused layer-3 projection)
    gemm_lsld<HC><<<(N + 63) / 64, 256, 0, stream>>>(bufB, W2, as2, ad2, bufA, ls, ld_, N);
    agg_k<true, true><<<N, 128, 0, stream>>>(bufA, ls, ld_, rp, csrs, csre, wd + 4, b2,
                                             bufB, W3, h3, N);
    // layer 3
    layer3_k<<<(N * 64 + 255) / 256, 256, 0, stream>>>(h3, rp, csrs, csre, wd, as3, ad3, b3,
                                                       (float*)d_out, N);
}

// Round 5
// 481.074 us; speedup vs baseline: 2.0732x; 1.0083x over previous
//
#include <hip/hip_runtime.h>
#include <hip/hip_bf16.h>

#define NNODES 50000
#define NEDGES 1600000
#define ETOT   (NNODES + NEDGES)
#define FIN    256
#define HC     128
#define NEG    0.2f
#define DEGCAP 128
#define ALP    (DEGCAP + 8)

// ---------------- CSR build (single atomic per edge) ----------------

__global__ void rank_k(const int* __restrict__ ei, int* __restrict__ rank,
                       int* __restrict__ deg, int E) {
    int i = blockIdx.x * blockDim.x + threadIdx.x;
    if (i < E) rank[i] = atomicAdd(&deg[ei[E + i]], 1);
}

// exclusive scan of (deg[i]+1)  — +1 reserves the self-loop slot per node
__global__ void scan_block(const int* __restrict__ deg, int* __restrict__ out,
                           int* __restrict__ bsum, int n) {
    __shared__ int sh[256];
    int t = threadIdx.x;
    int i = blockIdx.x * 256 + t;
    int v = (i < n) ? (deg[i] + 1) : 0;
    sh[t] = v;
    __syncthreads();
    for (int o = 1; o < 256; o <<= 1) {
        int a = (t >= o) ? sh[t - o] : 0;
        __syncthreads();
        sh[t] += a;
        __syncthreads();
    }
    if (i < n) out[i] = sh[t] - v;
    if (t == 255) bsum[blockIdx.x] = sh[255];
}

__global__ void scan_top(int* __restrict__ bsum, int nb) {
    __shared__ int sh[256];
    int t = threadIdx.x;
    int v = (t < nb) ? bsum[t] : 0;
    sh[t] = v;
    __syncthreads();
    for (int o = 1; o < 256; o <<= 1) {
        int a = (t >= o) ? sh[t - o] : 0;
        __syncthreads();
        sh[t] += a;
        __syncthreads();
    }
    if (t < nb) bsum[t] = sh[t] - v;
}

__global__ void scan_add(int* __restrict__ rp, const int* __restrict__ boff,
                         int n, int etot) {
    int i = blockIdx.x * blockDim.x + threadIdx.x;
    if (i < n)      rp[i] += boff[i >> 8];
    else if (i == n) rp[n] = etot;
}

__global__ void scatter_k(const int* __restrict__ ei, const float* __restrict__ ea,
                          const int* __restrict__ rp, const int* __restrict__ rank,
                          int* __restrict__ csr_src, float* __restrict__ csr_ea, int E) {
    int i = blockIdx.x * blockDim.x + threadIdx.x;
    if (i < E) {
        int d = ei[E + i];
        int pos = rp[d] + rank[i];
        csr_src[pos] = ei[i];
        csr_ea[pos] = ea[i];
    }
}

__global__ __launch_bounds__(256) void selfloop_k(const int* __restrict__ rp,
                                                  int* __restrict__ csr_src,
                                                  float* __restrict__ csr_ea, int n) {
    int wid = (blockIdx.x * blockDim.x + threadIdx.x) >> 6;
    int lane = threadIdx.x & 63;
    if (wid >= n) return;
    int beg = rp[wid], end = rp[wid + 1] - 1;
    float s = 0.f;
    for (int j = beg + lane; j < end; j += 64) s += csr_ea[j];
    for (int o = 32; o; o >>= 1) s += __shfl_xor(s, o, 64);
    if (lane == 0) {
        csr_ea[end] = s / fmaxf((float)(end - beg), 1.0f);
        csr_src[end] = wid;
    }
}

__global__ void wedot_k(const float* We1, const float* ae1,
                        const float* We2, const float* ae2,
                        const float* We3, const float* ae3,
                        float* __restrict__ wedot) {
    int t = threadIdx.x;
    float p1 = We1[t] * ae1[t];
    float p2 = We2[t] * ae2[t];
    for (int o = 16; o; o >>= 1) {
        p1 += __shfl_xor(p1, o, 32);
        p2 += __shfl_xor(p2, o, 32);
    }
    if ((t & 31) == 0) {
        wedot[t >> 5] = p1;
        wedot[4 + (t >> 5)] = p2;
    }
    if (t == 0) wedot[8] = We3[0] * ae3[0];
}

// ---------------- register-blocked GEMM + ls/ld epilogue ----------------
template <int K>
__global__ __launch_bounds__(256) void gemm_lsld(
        const float* __restrict__ x, const float* __restrict__ W,
        const float* __restrict__ a_s, const float* __restrict__ a_d,
        float* __restrict__ h, float* __restrict__ ls, float* __restrict__ ld_,
        int n) {
    constexpr int BM = 64, BK = 32;
    __shared__ float xsT[BK][BM];   // element (k,m) stored at xsT[k][m ^ ((k&7)<<2)]
    __shared__ float ws[BK][HC];
    int t = threadIdx.x;
    int tx = t & 31;
    int ty = t >> 5;
    int r0 = blockIdx.x * BM;

    float acc[8][4];
#pragma unroll
    for (int r = 0; r < 8; r++)
#pragma unroll
        for (int c = 0; c < 4; c++) acc[r][c] = 0.f;

    for (int kc = 0; kc < K; kc += BK) {
        __syncthreads();
#pragma unroll
        for (int q = 0; q < 2; q++) {
            int idx = q * 256 + t;
            int m = idx >> 3;
            int k4 = (idx & 7) * 4;
            int row = r0 + m;
            float4 v = (row < n) ? *(const float4*)&x[(size_t)row * K + kc + k4]
                                 : make_float4(0.f, 0.f, 0.f, 0.f);
            float vv[4] = {v.x, v.y, v.z, v.w};
#pragma unroll
            for (int j = 0; j < 4; j++) {
                int k = k4 + j;
                xsT[k][m ^ ((k & 7) << 2)] = vv[j];
            }
        }
#pragma unroll
        for (int q = 0; q < 4; q++) {
            int idx = q * 256 + t;
            int k = idx >> 5;
            int n4 = (idx & 31) * 4;
            *(float4*)&ws[k][n4] = *(const float4*)&W[(size_t)(kc + k) * HC + n4];
        }
        __syncthreads();
#pragma unroll
        for (int kk = 0; kk < BK; kk++) {
            int s = (kk & 7) << 2;
            float4 a0 = *(const float4*)&xsT[kk][(8 * ty) ^ s];
            float4 a1 = *(const float4*)&xsT[kk][(8 * ty + 4) ^ s];
            float4 w0 = *(const float4*)&ws[kk][4 * tx];
            float a[8] = {a0.x, a0.y, a0.z, a0.w, a1.x, a1.y, a1.z, a1.w};
            float wv[4] = {w0.x, w0.y, w0.z, w0.w};
#pragma unroll
            for (int r = 0; r < 8; r++)
#pragma unroll
                for (int c = 0; c < 4; c++)
                    acc[r][c] = fmaf(a[r], wv[c], acc[r][c]);
        }
    }

    int head = tx >> 3;
    float4 sa4 = *(const float4*)&a_s[4 * tx];
    float4 sd4 = *(const float4*)&a_d[4 * tx];
    float sa[4] = {sa4.x, sa4.y, sa4.z, sa4.w};
    float sd[4] = {sd4.x, sd4.y, sd4.z, sd4.w};
#pragma unroll
    for (int r = 0; r < 8; r++) {
        int row = r0 + 8 * ty + r;
        if (row >= n) break;
        float4 o = make_float4(acc[r][0], acc[r][1], acc[r][2], acc[r][3]);
        *(float4*)&h[(size_t)row * HC + 4 * tx] = o;
        float p = acc[r][0] * sa[0] + acc[r][1] * sa[1] + acc[r][2] * sa[2] + acc[r][3] * sa[3];
        float q = acc[r][0] * sd[0] + acc[r][1] * sd[1] + acc[r][2] * sd[2] + acc[r][3] * sd[3];
        p += __shfl_xor(p, 1); q += __shfl_xor(q, 1);
        p += __shfl_xor(p, 2); q += __shfl_xor(q, 2);
        p += __shfl_xor(p, 4); q += __shfl_xor(q, 4);
        if ((tx & 7) == 0) {
            ls[row * 4 + head] = p;
            ld_[row * 4 + head] = q;
        }
    }
}

// ---------------- per-node softmax aggregation (row-per-group gather) ----------------
template <bool RELU, bool FUSE3>
__global__ __launch_bounds__(128) void agg_k(
        const float* __restrict__ h, const float* __restrict__ ls,
        const float* __restrict__ ld_, const int* __restrict__ row_ptr,
        const int* __restrict__ csr_src, const float* __restrict__ csr_ea,
        const float* __restrict__ wedot, const float* __restrict__ bias,
        float* __restrict__ out, const float* __restrict__ W3,
        float* __restrict__ h3, int n) {
    __shared__ float albuf[4][ALP];      // padded: alpha broadcast is conflict-free
    __shared__ int srcbuf[DEGCAP];
    __shared__ float pacc[4][HC];
    __shared__ float hsuminv[4];
    int nid = blockIdx.x;
    int t = threadIdx.x, head = t >> 5, lane = t & 31;
    int beg = row_ptr[nid], end = row_ptr[nid + 1];
    int deg = end - beg;
    float ldn = ld_[nid * 4 + head];
    float wd = wedot[head];

    float v;
    if (deg <= DEGCAP) {
        // phase A: logits in registers (static-indexed), per-head max
        float lgr[4];
        float mx = -1e30f;
#pragma unroll
        for (int i = 0; i < 4; i++) {
            int e = lane + 32 * i;
            float lg = -1e30f;
            if (e < deg) {
                int s = csr_src[beg + e];
                if (head == 0) srcbuf[e] = s;
                lg = ls[s * 4 + head] + ldn + csr_ea[beg + e] * wd;
                lg = lg > 0.f ? lg : NEG * lg;
            }
            lgr[i] = lg;
            mx = fmaxf(mx, lg);
        }
        for (int o = 16; o; o >>= 1) mx = fmaxf(mx, __shfl_xor(mx, o, 32));

        // phase B: exp -> albuf, per-head sum
        float sum = 0.f;
#pragma unroll
        for (int i = 0; i < 4; i++) {
            int e = lane + 32 * i;
            if (e < deg) {
                float p = __expf(lgr[i] - mx);
                albuf[head][e] = p;
                sum += p;
            }
        }
        for (int o = 16; o; o >>= 1) sum += __shfl_xor(sum, o, 32);
        if (lane == 0) hsuminv[head] = 1.f / (sum + 1e-16f);
        __syncthreads();

        // phase C: group g = head handles edges g, g+4, ... ; lane holds 4 channels
        const float* al = albuf[lane >> 3];
        float4 acc0 = make_float4(0.f, 0.f, 0.f, 0.f);
        float4 acc1 = make_float4(0.f, 0.f, 0.f, 0.f);
        int e = head;
        for (; e + 4 < deg; e += 8) {
            int s0 = srcbuf[e], s1 = srcbuf[e + 4];
            float4 h0 = *(const float4*)&h[(size_t)s0 * HC + 4 * lane];
            float4 h1 = *(const float4*)&h[(size_t)s1 * HC + 4 * lane];
            float a0 = al[e], a1 = al[e + 4];
            acc0.x = fmaf(a0, h0.x, acc0.x);
            acc0.y = fmaf(a0, h0.y, acc0.y);
            acc0.z = fmaf(a0, h0.z, acc0.z);
            acc0.w = fmaf(a0, h0.w, acc0.w);
            acc1.x = fmaf(a1, h1.x, acc1.x);
            acc1.y = fmaf(a1, h1.y, acc1.y);
            acc1.z = fmaf(a1, h1.z, acc1.z);
            acc1.w = fmaf(a1, h1.w, acc1.w);
        }
        for (; e < deg; e += 4) {
            int s0 = srcbuf[e];
            float4 h0 = *(const float4*)&h[(size_t)s0 * HC + 4 * lane];
            float a0 = al[e];
            acc0.x = fmaf(a0, h0.x, acc0.x);
            acc0.y = fmaf(a0, h0.y, acc0.y);
            acc0.z = fmaf(a0, h0.z, acc0.z);
            acc0.w = fmaf(a0, h0.w, acc0.w);
        }
        acc0.x += acc1.x; acc0.y += acc1.y; acc0.z += acc1.z; acc0.w += acc1.w;
        *(float4*)&pacc[head][4 * lane] = acc0;
        __syncthreads();

        float inv = hsuminv[head];   // channel t's head == t>>5 == head
        v = (pacc[0][t] + pacc[1][t] + pacc[2][t] + pacc[3][t]) * inv + bias[t];
    } else {
        // fallback (deg > DEGCAP): recompute path, never hit for this graph
        float mx = -1e30f;
        for (int j = beg + lane; j < end; j += 32) {
            int s = csr_src[j];
            float lg = ls[s * 4 + head] + ldn + csr_ea[j] * wd;
            lg = lg > 0.f ? lg : NEG * lg;
            mx = fmaxf(mx, lg);
        }
        for (int o = 16; o; o >>= 1) mx = fmaxf(mx, __shfl_xor(mx, o, 32));
        float sum = 0.f, acc = 0.f;
        for (int j = beg; j < end; j++) {
            int s = csr_src[j];
            float lg = ls[s * 4 + head] + ldn + csr_ea[j] * wd;
            lg = lg > 0.f ? lg : NEG * lg;
            float p = __expf(lg - mx);
            sum += p;
            acc = fmaf(p, h[(size_t)s * HC + t], acc);
        }
        v = acc / (sum + 1e-16f) + bias[t];
    }

    if (RELU) v = fmaxf(v, 0.f);
    out[(size_t)nid * HC + t] = v;

    if (FUSE3) {
        float p = v * W3[t];
        for (int o = 32; o; o >>= 1) p += __shfl_xor(p, o, 64);
        __shared__ float sh[2];
        if ((t & 63) == 0) sh[t >> 6] = p;
        __syncthreads();
        if (t == 0) h3[nid] = sh[0] + sh[1];
    }
}

// ---------------- layer 3 (1 head, 1 channel), wave per node ----------------
__global__ __launch_bounds__(256) void layer3_k(
        const float* __restrict__ h3, const int* __restrict__ row_ptr,
        const int* __restrict__ csr_src, const float* __restrict__ csr_ea,
        const float* __restrict__ wedot, const float* __restrict__ as3,
        const float* __restrict__ ad3, const float* __restrict__ b3,
        float* __restrict__ out, int n) {
    int wid = (blockIdx.x * blockDim.x + threadIdx.x) >> 6;
    int lane = threadIdx.x & 63;
    if (wid >= n) return;
    float A = as3[0], D = ad3[0], wd = wedot[8];
    int beg = row_ptr[wid], end = row_ptr[wid + 1];
    float hdn = h3[wid] * D;

    float mx = -1e30f;
    for (int j = beg + lane; j < end; j += 64) {
        float lg = h3[csr_src[j]] * A + hdn + csr_ea[j] * wd;
        lg = lg > 0.f ? lg : NEG * lg;
        mx = fmaxf(mx, lg);
    }
    for (int o = 32; o; o >>= 1) mx = fmaxf(mx, __shfl_xor(mx, o, 64));

    float sum = 0.f, num = 0.f;
    for (int j = beg + lane; j < end; j += 64) {
        float hv = h3[csr_src[j]];
        float lg = hv * A + hdn + csr_ea[j] * wd;
        lg = lg > 0.f ? lg : NEG * lg;
        float p = __expf(lg - mx);
        sum += p;
        num = fmaf(p, hv, num);
    }
    for (int o = 32; o; o >>= 1) {
        sum += __shfl_xor(sum, o, 64);
        num += __shfl_xor(num, o, 64);
    }
    if (lane == 0) out[wid] = num / (sum + 1e-16f) + b3[0];
}

// ---------------- launch ----------------

extern "C" void kernel_launch(void* const* d_in, const int* in_sizes, int n_in,
                              void* d_out, int out_size, void* d_ws, size_t ws_size,
                              hipStream_t stream) {
    const float* x   = (const float*)d_in[0];
    const int*   ei  = (const int*)d_in[1];
    const float* ea  = (const float*)d_in[2];
    const float* W1  = (const float*)d_in[3];
    const float* We1 = (const float*)d_in[4];
    const float* as1 = (const float*)d_in[5];
    const float* ad1 = (const float*)d_in[6];
    const float* ae1 = (const float*)d_in[7];
    const float* b1  = (const float*)d_in[8];
    const float* W2  = (const float*)d_in[9];
    const float* We2 = (const float*)d_in[10];
    const float* as2 = (const float*)d_in[11];
    const float* ad2 = (const float*)d_in[12];
    const float* ae2 = (const float*)d_in[13];
    const float* b2  = (const float*)d_in[14];
    const float* W3  = (const float*)d_in[15];
    const float* We3 = (const float*)d_in[16];
    const float* as3 = (const float*)d_in[17];
    const float* ad3 = (const float*)d_in[18];
    const float* ae3 = (const float*)d_in[19];
    const float* b3  = (const float*)d_in[20];

    const int N = NNODES, E = NEDGES, etot = ETOT;

    char* ws = (char*)d_ws;
    size_t o = 0;
    auto alloc = [&](size_t bytes) { size_t r = o; o = (o + bytes + 255) & ~(size_t)255; return r; };
    size_t o_deg   = alloc((size_t)N * 4);
    size_t zero_span = o;
    size_t o_rp    = alloc((size_t)(N + 1) * 4);
    size_t o_bsum  = alloc(256 * 4);
    size_t o_wd    = alloc(16 * 4);
    size_t o_rank  = alloc((size_t)E * 4);
    size_t o_csrs  = alloc((size_t)etot * 4);
    size_t o_csre  = alloc((size_t)etot * 4);
    size_t o_ls    = alloc((size_t)N * 4 * 4);
    size_t o_ld    = alloc((size_t)N * 4 * 4);
    size_t o_h3    = alloc((size_t)N * 4);
    size_t o_bufA  = alloc((size_t)N * HC * 4);
    size_t o_bufB  = alloc((size_t)N * HC * 4);

    int*   deg   = (int*)(ws + o_deg);
    int*   rp    = (int*)(ws + o_rp);
    int*   bsum  = (int*)(ws + o_bsum);
    float* wd    = (float*)(ws + o_wd);
    int*   rank  = (int*)(ws + o_rank);
    int*   csrs  = (int*)(ws + o_csrs);
    float* csre  = (float*)(ws + o_csre);
    float* ls    = (float*)(ws + o_ls);
    float* ld_   = (float*)(ws + o_ld);
    float* h3    = (float*)(ws + o_h3);
    float* bufA  = (float*)(ws + o_bufA);
    float* bufB  = (float*)(ws + o_bufB);

    hipMemsetAsync(ws, 0, zero_span, stream);

    int nb = (N + 255) / 256;
    rank_k<<<(E + 255) / 256, 256, 0, stream>>>(ei, rank, deg, E);
    scan_block<<<nb, 256, 0, stream>>>(deg, rp, bsum, N);
    scan_top<<<1, 256, 0, stream>>>(bsum, nb);
    scan_add<<<(N + 256) / 256, 256, 0, stream>>>(rp, bsum, N, etot);
    scatter_k<<<(E + 255) / 256, 256, 0, stream>>>(ei, ea, rp, rank, csrs, csre, E);
    selfloop_k<<<(N * 64 + 255) / 256, 256, 0, stream>>>(rp, csrs, csre, N);
    wedot_k<<<1, 128, 0, stream>>>(We1, ae1, We2, ae2, We3, ae3, wd);

    // layer 1
    gemm_lsld<FIN><<<(N + 63) / 64, 256, 0, stream>>>(x, W1, as1, ad1, bufA, ls, ld_, N);
    agg_k<true, false><<<N, 128, 0, stream>>>(bufA, ls, ld_, rp, csrs, csre, wd, b1,
                                              bufB, nullptr, nullptr, N);
    // layer 2 (+ fused layer-3 projection)
    gemm_lsld<HC><<<(N + 63) / 64, 256, 0, stream>>>(bufB, W2, as2, ad2, bufA, ls, ld_, N);
    agg_k<true, true><<<N, 128, 0, stream>>>(bufA, ls, ld_, rp, csrs, csre, wd + 4, b2,
                                             bufB, W3, h3, N);
    // layer 3
    layer3_k<<<(N * 64 + 255) / 256, 256, 0, stream>>>(h3, rp, csrs, csre, wd, as3, ad3, b3,
                                                       (float*)d_out, N);
}

// Round 6
// 391.678 us; speedup vs baseline: 2.5463x; 1.2282x over previous
//
#include <hip/hip_runtime.h>
#include <hip/hip_bf16.h>
#include <hip/hip_fp16.h>

#define NNODES 50000
#define NEDGES 1600000
#define ETOT   (NNODES + NEDGES)
#define FIN    256
#define HC     128
#define NEG    0.2f
#define DEGCAP 128
#define ALP    (DEGCAP + 8)

// ---------------- CSR build (single atomic per edge) ----------------

__global__ void rank_k(const int* __restrict__ ei, int* __restrict__ rank,
                       int* __restrict__ deg, int E) {
    int i = blockIdx.x * blockDim.x + threadIdx.x;
    if (i < E) rank[i] = atomicAdd(&deg[ei[E + i]], 1);
}

// exclusive scan of (deg[i]+1)  — +1 reserves the self-loop slot per node
__global__ void scan_block(const int* __restrict__ deg, int* __restrict__ out,
                           int* __restrict__ bsum, int n) {
    __shared__ int sh[256];
    int t = threadIdx.x;
    int i = blockIdx.x * 256 + t;
    int v = (i < n) ? (deg[i] + 1) : 0;
    sh[t] = v;
    __syncthreads();
    for (int o = 1; o < 256; o <<= 1) {
        int a = (t >= o) ? sh[t - o] : 0;
        __syncthreads();
        sh[t] += a;
        __syncthreads();
    }
    if (i < n) out[i] = sh[t] - v;
    if (t == 255) bsum[blockIdx.x] = sh[255];
}

__global__ void scan_top(int* __restrict__ bsum, int nb) {
    __shared__ int sh[256];
    int t = threadIdx.x;
    int v = (t < nb) ? bsum[t] : 0;
    sh[t] = v;
    __syncthreads();
    for (int o = 1; o < 256; o <<= 1) {
        int a = (t >= o) ? sh[t - o] : 0;
        __syncthreads();
        sh[t] += a;
        __syncthreads();
    }
    if (t < nb) bsum[t] = sh[t] - v;
}

__global__ void scan_add(int* __restrict__ rp, const int* __restrict__ boff,
                         int n, int etot) {
    int i = blockIdx.x * blockDim.x + threadIdx.x;
    if (i < n)      rp[i] += boff[i >> 8];
    else if (i == n) rp[n] = etot;
}

__global__ void scatter_k(const int* __restrict__ ei, const float* __restrict__ ea,
                          const int* __restrict__ rp, const int* __restrict__ rank,
                          int* __restrict__ csr_src, float* __restrict__ csr_ea, int E) {
    int i = blockIdx.x * blockDim.x + threadIdx.x;
    if (i < E) {
        int d = ei[E + i];
        int pos = rp[d] + rank[i];
        csr_src[pos] = ei[i];
        csr_ea[pos] = ea[i];
    }
}

__global__ __launch_bounds__(256) void selfloop_k(const int* __restrict__ rp,
                                                  int* __restrict__ csr_src,
                                                  float* __restrict__ csr_ea, int n) {
    int wid = (blockIdx.x * blockDim.x + threadIdx.x) >> 6;
    int lane = threadIdx.x & 63;
    if (wid >= n) return;
    int beg = rp[wid], end = rp[wid + 1] - 1;
    float s = 0.f;
    for (int j = beg + lane; j < end; j += 64) s += csr_ea[j];
    for (int o = 32; o; o >>= 1) s += __shfl_xor(s, o, 64);
    if (lane == 0) {
        csr_ea[end] = s / fmaxf((float)(end - beg), 1.0f);
        csr_src[end] = wid;
    }
}

__global__ void wedot_k(const float* We1, const float* ae1,
                        const float* We2, const float* ae2,
                        const float* We3, const float* ae3,
                        float* __restrict__ wedot) {
    int t = threadIdx.x;
    float p1 = We1[t] * ae1[t];
    float p2 = We2[t] * ae2[t];
    for (int o = 16; o; o >>= 1) {
        p1 += __shfl_xor(p1, o, 32);
        p2 += __shfl_xor(p2, o, 32);
    }
    if ((t & 31) == 0) {
        wedot[t >> 5] = p1;
        wedot[4 + (t >> 5)] = p2;
    }
    if (t == 0) wedot[8] = We3[0] * ae3[0];
}

// ---------------- register-blocked GEMM + ls/ld epilogue (h stored fp16) ----------------
template <int K>
__global__ __launch_bounds__(256) void gemm_lsld(
        const float* __restrict__ x, const float* __restrict__ W,
        const float* __restrict__ a_s, const float* __restrict__ a_d,
        __half* __restrict__ h, float* __restrict__ ls, float* __restrict__ ld_,
        int n) {
    constexpr int BM = 64, BK = 32;
    __shared__ float xsT[BK][BM];   // element (k,m) stored at xsT[k][m ^ ((k&7)<<2)]
    __shared__ float ws[BK][HC];
    int t = threadIdx.x;
    int tx = t & 31;
    int ty = t >> 5;
    int r0 = blockIdx.x * BM;

    float acc[8][4];
#pragma unroll
    for (int r = 0; r < 8; r++)
#pragma unroll
        for (int c = 0; c < 4; c++) acc[r][c] = 0.f;

    for (int kc = 0; kc < K; kc += BK) {
        __syncthreads();
#pragma unroll
        for (int q = 0; q < 2; q++) {
            int idx = q * 256 + t;
            int m = idx >> 3;
            int k4 = (idx & 7) * 4;
            int row = r0 + m;
            float4 v = (row < n) ? *(const float4*)&x[(size_t)row * K + kc + k4]
                                 : make_float4(0.f, 0.f, 0.f, 0.f);
            float vv[4] = {v.x, v.y, v.z, v.w};
#pragma unroll
            for (int j = 0; j < 4; j++) {
                int k = k4 + j;
                xsT[k][m ^ ((k & 7) << 2)] = vv[j];
            }
        }
#pragma unroll
        for (int q = 0; q < 4; q++) {
            int idx = q * 256 + t;
            int k = idx >> 5;
            int n4 = (idx & 31) * 4;
            *(float4*)&ws[k][n4] = *(const float4*)&W[(size_t)(kc + k) * HC + n4];
        }
        __syncthreads();
#pragma unroll
        for (int kk = 0; kk < BK; kk++) {
            int s = (kk & 7) << 2;
            float4 a0 = *(const float4*)&xsT[kk][(8 * ty) ^ s];
            float4 a1 = *(const float4*)&xsT[kk][(8 * ty + 4) ^ s];
            float4 w0 = *(const float4*)&ws[kk][4 * tx];
            float a[8] = {a0.x, a0.y, a0.z, a0.w, a1.x, a1.y, a1.z, a1.w};
            float wv[4] = {w0.x, w0.y, w0.z, w0.w};
#pragma unroll
            for (int r = 0; r < 8; r++)
#pragma unroll
                for (int c = 0; c < 4; c++)
                    acc[r][c] = fmaf(a[r], wv[c], acc[r][c]);
        }
    }

    int head = tx >> 3;
    float4 sa4 = *(const float4*)&a_s[4 * tx];
    float4 sd4 = *(const float4*)&a_d[4 * tx];
    float sa[4] = {sa4.x, sa4.y, sa4.z, sa4.w};
    float sd[4] = {sd4.x, sd4.y, sd4.z, sd4.w};
#pragma unroll
    for (int r = 0; r < 8; r++) {
        int row = r0 + 8 * ty + r;
        if (row >= n) break;
        union { __half2 h2[2]; int2 i2; } u;
        u.h2[0] = __floats2half2_rn(acc[r][0], acc[r][1]);
        u.h2[1] = __floats2half2_rn(acc[r][2], acc[r][3]);
        *(int2*)&h[(size_t)row * HC + 4 * tx] = u.i2;
        float p = acc[r][0] * sa[0] + acc[r][1] * sa[1] + acc[r][2] * sa[2] + acc[r][3] * sa[3];
        float q = acc[r][0] * sd[0] + acc[r][1] * sd[1] + acc[r][2] * sd[2] + acc[r][3] * sd[3];
        p += __shfl_xor(p, 1); q += __shfl_xor(q, 1);
        p += __shfl_xor(p, 2); q += __shfl_xor(q, 2);
        p += __shfl_xor(p, 4); q += __shfl_xor(q, 4);
        if ((tx & 7) == 0) {
            ls[row * 4 + head] = p;
            ld_[row * 4 + head] = q;
        }
    }
}

// ---------------- per-node softmax aggregation (fp16 row gather) ----------------
template <bool RELU, bool FUSE3>
__global__ __launch_bounds__(128) void agg_k(
        const __half* __restrict__ h, const float* __restrict__ ls,
        const float* __restrict__ ld_, const int* __restrict__ row_ptr,
        const int* __restrict__ csr_src, const float* __restrict__ csr_ea,
        const float* __restrict__ wedot, const float* __restrict__ bias,
        float* __restrict__ out, const float* __restrict__ W3,
        float* __restrict__ h3, int n) {
    __shared__ float albuf[4][ALP];      // padded: alpha broadcast is conflict-free
    __shared__ int srcbuf[DEGCAP];
    __shared__ float pacc[4][HC];
    __shared__ float hsuminv[4];
    int nid = blockIdx.x;
    int t = threadIdx.x, head = t >> 5, lane = t & 31;
    int beg = row_ptr[nid], end = row_ptr[nid + 1];
    int deg = end - beg;
    float ldn = ld_[nid * 4 + head];
    float wd = wedot[head];

    float v;
    if (deg <= DEGCAP) {
        // phase A: logits in registers (static-indexed), per-head max
        float lgr[4];
        float mx = -1e30f;
#pragma unroll
        for (int i = 0; i < 4; i++) {
            int e = lane + 32 * i;
            float lg = -1e30f;
            if (e < deg) {
                int s = csr_src[beg + e];
                if (head == 0) srcbuf[e] = s;
                lg = ls[s * 4 + head] + ldn + csr_ea[beg + e] * wd;
                lg = lg > 0.f ? lg : NEG * lg;
            }
            lgr[i] = lg;
            mx = fmaxf(mx, lg);
        }
        for (int o = 16; o; o >>= 1) mx = fmaxf(mx, __shfl_xor(mx, o, 32));

        // phase B: exp -> albuf, per-head sum
        float sum = 0.f;
#pragma unroll
        for (int i = 0; i < 4; i++) {
            int e = lane + 32 * i;
            if (e < deg) {
                float p = __expf(lgr[i] - mx);
                albuf[head][e] = p;
                sum += p;
            }
        }
        for (int o = 16; o; o >>= 1) sum += __shfl_xor(sum, o, 32);
        if (lane == 0) hsuminv[head] = 1.f / (sum + 1e-16f);
        __syncthreads();

        // phase C: group g = head handles edges g, g+4, ...; lane holds 4 channels (8B fp16)
        const float* al = albuf[lane >> 3];
        float4 acc0 = make_float4(0.f, 0.f, 0.f, 0.f);
        float4 acc1 = make_float4(0.f, 0.f, 0.f, 0.f);
        int e = head;
        for (; e + 4 < deg; e += 8) {
            int s0 = srcbuf[e], s1 = srcbuf[e + 4];
            int2 r0v = *(const int2*)&h[(size_t)s0 * HC + 4 * lane];
            int2 r1v = *(const int2*)&h[(size_t)s1 * HC + 4 * lane];
            float2 f00 = __half22float2(*reinterpret_cast<const __half2*>(&r0v.x));
            float2 f01 = __half22float2(*reinterpret_cast<const __half2*>(&r0v.y));
            float2 f10 = __half22float2(*reinterpret_cast<const __half2*>(&r1v.x));
            float2 f11 = __half22float2(*reinterpret_cast<const __half2*>(&r1v.y));
            float a0 = al[e], a1 = al[e + 4];
            acc0.x = fmaf(a0, f00.x, acc0.x);
            acc0.y = fmaf(a0, f00.y, acc0.y);
            acc0.z = fmaf(a0, f01.x, acc0.z);
            acc0.w = fmaf(a0, f01.y, acc0.w);
            acc1.x = fmaf(a1, f10.x, acc1.x);
            acc1.y = fmaf(a1, f10.y, acc1.y);
            acc1.z = fmaf(a1, f11.x, acc1.z);
            acc1.w = fmaf(a1, f11.y, acc1.w);
        }
        for (; e < deg; e += 4) {
            int s0 = srcbuf[e];
            int2 r0v = *(const int2*)&h[(size_t)s0 * HC + 4 * lane];
            float2 f00 = __half22float2(*reinterpret_cast<const __half2*>(&r0v.x));
            float2 f01 = __half22float2(*reinterpret_cast<const __half2*>(&r0v.y));
            float a0 = al[e];
            acc0.x = fmaf(a0, f00.x, acc0.x);
            acc0.y = fmaf(a0, f00.y, acc0.y);
            acc0.z = fmaf(a0, f01.x, acc0.z);
            acc0.w = fmaf(a0, f01.y, acc0.w);
        }
        acc0.x += acc1.x; acc0.y += acc1.y; acc0.z += acc1.z; acc0.w += acc1.w;
        *(float4*)&pacc[head][4 * lane] = acc0;
        __syncthreads();

        float inv = hsuminv[head];
        v = (pacc[0][t] + pacc[1][t] + pacc[2][t] + pacc[3][t]) * inv + bias[t];
    } else {
        // fallback (deg > DEGCAP): recompute path, never hit for this graph
        float mx = -1e30f;
        for (int j = beg + lane; j < end; j += 32) {
            int s = csr_src[j];
            float lg = ls[s * 4 + head] + ldn + csr_ea[j] * wd;
            lg = lg > 0.f ? lg : NEG * lg;
            mx = fmaxf(mx, lg);
        }
        for (int o = 16; o; o >>= 1) mx = fmaxf(mx, __shfl_xor(mx, o, 32));
        float sum = 0.f, acc = 0.f;
        for (int j = beg; j < end; j++) {
            int s = csr_src[j];
            float lg = ls[s * 4 + head] + ldn + csr_ea[j] * wd;
            lg = lg > 0.f ? lg : NEG * lg;
            float p = __expf(lg - mx);
            sum += p;
            acc = fmaf(p, __half2float(h[(size_t)s * HC + t]), acc);
        }
        v = acc / (sum + 1e-16f) + bias[t];
    }

    if (RELU) v = fmaxf(v, 0.f);
    if (!FUSE3) out[(size_t)nid * HC + t] = v;   // FUSE3: only h3 is consumed downstream

    if (FUSE3) {
        float p = v * W3[t];
        for (int o = 32; o; o >>= 1) p += __shfl_xor(p, o, 64);
        __shared__ float sh[2];
        if ((t & 63) == 0) sh[t >> 6] = p;
        __syncthreads();
        if (t == 0) h3[nid] = sh[0] + sh[1];
    }
}

// ---------------- layer 3 (1 head, 1 channel), wave per node ----------------
__global__ __launch_bounds__(256) void layer3_k(
        const float* __restrict__ h3, const int* __restrict__ row_ptr,
        const int* __restrict__ csr_src, const float* __restrict__ csr_ea,
        const float* __restrict__ wedot, const float* __restrict__ as3,
        const float* __restrict__ ad3, const float* __restrict__ b3,
        float* __restrict__ out, int n) {
    int wid = (blockIdx.x * blockDim.x + threadIdx.x) >> 6;
    int lane = threadIdx.x & 63;
    if (wid >= n) return;
    float A = as3[0], D = ad3[0], wd = wedot[8];
    int beg = row_ptr[wid], end = row_ptr[wid + 1];
    float hdn = h3[wid] * D;

    float mx = -1e30f;
    for (int j = beg + lane; j < end; j += 64) {
        float lg = h3[csr_src[j]] * A + hdn + csr_ea[j] * wd;
        lg = lg > 0.f ? lg : NEG * lg;
        mx = fmaxf(mx, lg);
    }
    for (int o = 32; o; o >>= 1) mx = fmaxf(mx, __shfl_xor(mx, o, 64));

    float sum = 0.f, num = 0.f;
    for (int j = beg + lane; j < end; j += 64) {
        float hv = h3[csr_src[j]];
        float lg = hv * A + hdn + csr_ea[j] * wd;
        lg = lg > 0.f ? lg : NEG * lg;
        float p = __expf(lg - mx);
        sum += p;
        num = fmaf(p, hv, num);
    }
    for (int o = 32; o; o >>= 1) {
        sum += __shfl_xor(sum, o, 64);
        num += __shfl_xor(num, o, 64);
    }
    if (lane == 0) out[wid] = num / (sum + 1e-16f) + b3[0];
}

// ---------------- launch ----------------

extern "C" void kernel_launch(void* const* d_in, const int* in_sizes, int n_in,
                              void* d_out, int out_size, void* d_ws, size_t ws_size,
                              hipStream_t stream) {
    const float* x   = (const float*)d_in[0];
    const int*   ei  = (const int*)d_in[1];
    const float* ea  = (const float*)d_in[2];
    const float* W1  = (const float*)d_in[3];
    const float* We1 = (const float*)d_in[4];
    const float* as1 = (const float*)d_in[5];
    const float* ad1 = (const float*)d_in[6];
    const float* ae1 = (const float*)d_in[7];
    const float* b1  = (const float*)d_in[8];
    const float* W2  = (const float*)d_in[9];
    const float* We2 = (const float*)d_in[10];
    const float* as2 = (const float*)d_in[11];
    const float* ad2 = (const float*)d_in[12];
    const float* ae2 = (const float*)d_in[13];
    const float* b2  = (const float*)d_in[14];
    const float* W3  = (const float*)d_in[15];
    const float* We3 = (const float*)d_in[16];
    const float* as3 = (const float*)d_in[17];
    const float* ad3 = (const float*)d_in[18];
    const float* ae3 = (const float*)d_in[19];
    const float* b3  = (const float*)d_in[20];

    const int N = NNODES, E = NEDGES, etot = ETOT;

    char* ws = (char*)d_ws;
    size_t o = 0;
    auto alloc = [&](size_t bytes) { size_t r = o; o = (o + bytes + 255) & ~(size_t)255; return r; };
    size_t o_deg   = alloc((size_t)N * 4);
    size_t zero_span = o;
    size_t o_rp    = alloc((size_t)(N + 1) * 4);
    size_t o_bsum  = alloc(256 * 4);
    size_t o_wd    = alloc(16 * 4);
    size_t o_rank  = alloc((size_t)E * 4);
    size_t o_csrs  = alloc((size_t)etot * 4);
    size_t o_csre  = alloc((size_t)etot * 4);
    size_t o_ls    = alloc((size_t)N * 4 * 4);
    size_t o_ld    = alloc((size_t)N * 4 * 4);
    size_t o_h3    = alloc((size_t)N * 4);
    size_t o_h16   = alloc((size_t)N * HC * 2);   // fp16 feature rows (both layers)
    size_t o_bufB  = alloc((size_t)N * HC * 4);   // fp32 agg-1 output

    int*    deg   = (int*)(ws + o_deg);
    int*    rp    = (int*)(ws + o_rp);
    int*    bsum  = (int*)(ws + o_bsum);
    float*  wd    = (float*)(ws + o_wd);
    int*    rank  = (int*)(ws + o_rank);
    int*    csrs  = (int*)(ws + o_csrs);
    float*  csre  = (float*)(ws + o_csre);
    float*  ls    = (float*)(ws + o_ls);
    float*  ld_   = (float*)(ws + o_ld);
    float*  h3    = (float*)(ws + o_h3);
    __half* h16   = (__half*)(ws + o_h16);
    float*  bufB  = (float*)(ws + o_bufB);

    hipMemsetAsync(ws, 0, zero_span, stream);

    int nb = (N + 255) / 256;
    rank_k<<<(E + 255) / 256, 256, 0, stream>>>(ei, rank, deg, E);
    scan_block<<<nb, 256, 0, stream>>>(deg, rp, bsum, N);
    scan_top<<<1, 256, 0, stream>>>(bsum, nb);
    scan_add<<<(N + 256) / 256, 256, 0, stream>>>(rp, bsum, N, etot);
    scatter_k<<<(E + 255) / 256, 256, 0, stream>>>(ei, ea, rp, rank, csrs, csre, E);
    selfloop_k<<<(N * 64 + 255) / 256, 256, 0, stream>>>(rp, csrs, csre, N);
    wedot_k<<<1, 128, 0, stream>>>(We1, ae1, We2, ae2, We3, ae3, wd);

    // layer 1
    gemm_lsld<FIN><<<(N + 63) / 64, 256, 0, stream>>>(x, W1, as1, ad1, h16, ls, ld_, N);
    agg_k<true, false><<<N, 128, 0, stream>>>(h16, ls, ld_, rp, csrs, csre, wd, b1,
                                              bufB, nullptr, nullptr, N);
    // layer 2 (+ fused layer-3 projection)
    gemm_lsld<HC><<<(N + 63) / 64, 256, 0, stream>>>(bufB, W2, as2, ad2, h16, ls, ld_, N);
    agg_k<true, true><<<N, 128, 0, stream>>>(h16, ls, ld_, rp, csrs, csre, wd + 4, b2,
                                             nullptr, W3, h3, N);
    // layer 3
    layer3_k<<<(N * 64 + 255) / 256, 256, 0, stream>>>(h3, rp, csrs, csre, wd, as3, ad3, b3,
                                                       (float*)d_out, N);
}

// Round 7
// 349.184 us; speedup vs baseline: 2.8562x; 1.1217x over previous
//
#include <hip/hip_runtime.h>
#include <hip/hip_bf16.h>
#include <hip/hip_fp16.h>

#define NNODES 50000
#define NEDGES 1600000
#define ETOT   (NNODES + NEDGES)
#define FIN    256
#define HC     128
#define NEG    0.2f
#define DEGCAP 128
#define ALP    (DEGCAP + 8)

// ---------------- CSR build (single atomic per edge) ----------------

__global__ void rank_k(const int* __restrict__ ei, int* __restrict__ rank,
                       int* __restrict__ deg, int E) {
    int i = blockIdx.x * blockDim.x + threadIdx.x;
    if (i < E) rank[i] = atomicAdd(&deg[ei[E + i]], 1);
}

// exclusive scan of (deg[i]+1)  — +1 reserves the self-loop slot per node
__global__ void scan_block(const int* __restrict__ deg, int* __restrict__ out,
                           int* __restrict__ bsum, int n) {
    __shared__ int sh[256];
    int t = threadIdx.x;
    int i = blockIdx.x * 256 + t;
    int v = (i < n) ? (deg[i] + 1) : 0;
    sh[t] = v;
    __syncthreads();
    for (int o = 1; o < 256; o <<= 1) {
        int a = (t >= o) ? sh[t - o] : 0;
        __syncthreads();
        sh[t] += a;
        __syncthreads();
    }
    if (i < n) out[i] = sh[t] - v;
    if (t == 255) bsum[blockIdx.x] = sh[255];
}

__global__ void scan_top(int* __restrict__ bsum, int nb) {
    __shared__ int sh[256];
    int t = threadIdx.x;
    int v = (t < nb) ? bsum[t] : 0;
    sh[t] = v;
    __syncthreads();
    for (int o = 1; o < 256; o <<= 1) {
        int a = (t >= o) ? sh[t - o] : 0;
        __syncthreads();
        sh[t] += a;
        __syncthreads();
    }
    if (t < nb) bsum[t] = sh[t] - v;
}

__global__ void scan_add(int* __restrict__ rp, const int* __restrict__ boff,
                         int n, int etot) {
    int i = blockIdx.x * blockDim.x + threadIdx.x;
    if (i < n)      rp[i] += boff[i >> 8];
    else if (i == n) rp[n] = etot;
}

// atomic-free scatter into packed (src, ea) int2 CSR
__global__ void scatter_k(const int* __restrict__ ei, const float* __restrict__ ea,
                          const int* __restrict__ rp, const int* __restrict__ rank,
                          int2* __restrict__ csr, int E) {
    int i = blockIdx.x * blockDim.x + threadIdx.x;
    if (i < E) {
        int d = ei[E + i];
        int pos = rp[d] + rank[i];
        csr[pos] = make_int2(ei[i], __float_as_int(ea[i]));
    }
}

// self-loop slot: 8 lanes per node
__global__ __launch_bounds__(256) void selfloop_k(const int* __restrict__ rp,
                                                  int2* __restrict__ csr, int n) {
    int idx = blockIdx.x * blockDim.x + threadIdx.x;
    int node = idx >> 3, l = idx & 7;
    if (node >= n) return;
    int beg = rp[node], end = rp[node + 1] - 1;
    float s = 0.f;
    for (int j = beg + l; j < end; j += 8) s += __int_as_float(csr[j].y);
    s += __shfl_xor(s, 1, 8);
    s += __shfl_xor(s, 2, 8);
    s += __shfl_xor(s, 4, 8);
    if (l == 0)
        csr[end] = make_int2(node, __float_as_int(s / fmaxf((float)(end - beg), 1.0f)));
}

__global__ void wedot_k(const float* We1, const float* ae1,
                        const float* We2, const float* ae2,
                        const float* We3, const float* ae3,
                        float* __restrict__ wedot) {
    int t = threadIdx.x;
    float p1 = We1[t] * ae1[t];
    float p2 = We2[t] * ae2[t];
    for (int o = 16; o; o >>= 1) {
        p1 += __shfl_xor(p1, o, 32);
        p2 += __shfl_xor(p2, o, 32);
    }
    if ((t & 31) == 0) {
        wedot[t >> 5] = p1;
        wedot[4 + (t >> 5)] = p2;
    }
    if (t == 0) wedot[8] = We3[0] * ae3[0];
}

// ---------------- register-blocked GEMM + ls/ld epilogue (h stored fp16) ----------------
template <int K>
__global__ __launch_bounds__(256) void gemm_lsld(
        const float* __restrict__ x, const float* __restrict__ W,
        const float* __restrict__ a_s, const float* __restrict__ a_d,
        __half* __restrict__ h, float* __restrict__ ls, float* __restrict__ ld_,
        int n) {
    constexpr int BM = 64, BK = 32;
    __shared__ float xsT[BK][BM];   // element (k,m) stored at xsT[k][m ^ ((k&7)<<2)]
    __shared__ float ws[BK][HC];
    int t = threadIdx.x;
    int tx = t & 31;
    int ty = t >> 5;
    int r0 = blockIdx.x * BM;

    float acc[8][4];
#pragma unroll
    for (int r = 0; r < 8; r++)
#pragma unroll
        for (int c = 0; c < 4; c++) acc[r][c] = 0.f;

    for (int kc = 0; kc < K; kc += BK) {
        __syncthreads();
#pragma unroll
        for (int q = 0; q < 2; q++) {
            int idx = q * 256 + t;
            int m = idx >> 3;
            int k4 = (idx & 7) * 4;
            int row = r0 + m;
            float4 v = (row < n) ? *(const float4*)&x[(size_t)row * K + kc + k4]
                                 : make_float4(0.f, 0.f, 0.f, 0.f);
            float vv[4] = {v.x, v.y, v.z, v.w};
#pragma unroll
            for (int j = 0; j < 4; j++) {
                int k = k4 + j;
                xsT[k][m ^ ((k & 7) << 2)] = vv[j];
            }
        }
#pragma unroll
        for (int q = 0; q < 4; q++) {
            int idx = q * 256 + t;
            int k = idx >> 5;
            int n4 = (idx & 31) * 4;
            *(float4*)&ws[k][n4] = *(const float4*)&W[(size_t)(kc + k) * HC + n4];
        }
        __syncthreads();
#pragma unroll
        for (int kk = 0; kk < BK; kk++) {
            int s = (kk & 7) << 2;
            float4 a0 = *(const float4*)&xsT[kk][(8 * ty) ^ s];
            float4 a1 = *(const float4*)&xsT[kk][(8 * ty + 4) ^ s];
            float4 w0 = *(const float4*)&ws[kk][4 * tx];
            float a[8] = {a0.x, a0.y, a0.z, a0.w, a1.x, a1.y, a1.z, a1.w};
            float wv[4] = {w0.x, w0.y, w0.z, w0.w};
#pragma unroll
            for (int r = 0; r < 8; r++)
#pragma unroll
                for (int c = 0; c < 4; c++)
                    acc[r][c] = fmaf(a[r], wv[c], acc[r][c]);
        }
    }

    int head = tx >> 3;
    float4 sa4 = *(const float4*)&a_s[4 * tx];
    float4 sd4 = *(const float4*)&a_d[4 * tx];
    float sa[4] = {sa4.x, sa4.y, sa4.z, sa4.w};
    float sd[4] = {sd4.x, sd4.y, sd4.z, sd4.w};
#pragma unroll
    for (int r = 0; r < 8; r++) {
        int row = r0 + 8 * ty + r;
        if (row >= n) break;
        union { __half2 h2[2]; int2 i2; } u;
        u.h2[0] = __floats2half2_rn(acc[r][0], acc[r][1]);
        u.h2[1] = __floats2half2_rn(acc[r][2], acc[r][3]);
        *(int2*)&h[(size_t)row * HC + 4 * tx] = u.i2;
        float p = acc[r][0] * sa[0] + acc[r][1] * sa[1] + acc[r][2] * sa[2] + acc[r][3] * sa[3];
        float q = acc[r][0] * sd[0] + acc[r][1] * sd[1] + acc[r][2] * sd[2] + acc[r][3] * sd[3];
        p += __shfl_xor(p, 1); q += __shfl_xor(q, 1);
        p += __shfl_xor(p, 2); q += __shfl_xor(q, 2);
        p += __shfl_xor(p, 4); q += __shfl_xor(q, 4);
        if ((tx & 7) == 0) {
            ls[row * 4 + head] = p;
            ld_[row * 4 + head] = q;
        }
    }
}

// ---------------- per-node softmax aggregation (fp16 full-row gather) ----------------
template <bool RELU, bool FUSE3>
__global__ __launch_bounds__(128) void agg_k(
        const __half* __restrict__ h, const float* __restrict__ ls,
        const float* __restrict__ ld_, const int* __restrict__ row_ptr,
        const int2* __restrict__ csr,
        const float* __restrict__ wedot, const float* __restrict__ bias,
        float* __restrict__ out, const float* __restrict__ W3,
        float* __restrict__ h3, int n) {
    __shared__ float albuf[4][ALP];
    __shared__ int srcbuf[DEGCAP];       // pre-scaled row byte offsets (s*256)
    __shared__ float pacc[8][HC];
    __shared__ float hsuminv[4];
    int nid = blockIdx.x;
    int t = threadIdx.x, head = t >> 5, lane = t & 31;
    int beg = row_ptr[nid], end = row_ptr[nid + 1];
    int deg = end - beg;
    float ldn = ld_[nid * 4 + head];
    float wd = wedot[head];

    float v;
    if (deg <= DEGCAP) {
        // phase A: logits in registers, per-head max; head-0 wave caches byte offsets
        float lgr[4];
        float mx = -1e30f;
#pragma unroll
        for (int i = 0; i < 4; i++) {
            int e = lane + 32 * i;
            float lg = -1e30f;
            if (e < deg) {
                int2 ce = csr[beg + e];
                if (head == 0) srcbuf[e] = ce.x << 8;   // s * HC * 2 bytes
                lg = ls[ce.x * 4 + head] + ldn + __int_as_float(ce.y) * wd;
                lg = lg > 0.f ? lg : NEG * lg;
            }
            lgr[i] = lg;
            mx = fmaxf(mx, lg);
        }
        for (int o = 16; o; o >>= 1) mx = fmaxf(mx, __shfl_xor(mx, o, 32));

        // phase B: exp -> albuf, per-head sum
        float sum = 0.f;
#pragma unroll
        for (int i = 0; i < 4; i++) {
            int e = lane + 32 * i;
            if (e < deg) {
                float p = __expf(lgr[i] - mx);
                albuf[head][e] = p;
                sum += p;
            }
        }
        for (int o = 16; o; o >>= 1) sum += __shfl_xor(sum, o, 32);
        if (lane == 0) hsuminv[head] = 1.f / (sum + 1e-16f);
        __syncthreads();

        // phase C: 8 groups x 16 lanes; group g -> edges g, g+8, ...
        // lane loads 16B (8 fp16 channels) of the row: one dwordx4 per edge per group.
        int g = t >> 4, l = t & 15;
        int c0 = 8 * l;
        const float* al = albuf[c0 >> 5];
        const char* hb = (const char*)h + 16 * l;
        float acc[8];
#pragma unroll
        for (int j = 0; j < 8; j++) acc[j] = 0.f;
        int e = g;
        for (; e + 8 < deg; e += 16) {
            int o0 = srcbuf[e], o1 = srcbuf[e + 8];
            int4 r0 = *(const int4*)(hb + o0);
            int4 r1 = *(const int4*)(hb + o1);
            float a0 = al[e], a1 = al[e + 8];
            const __half2* p0 = (const __half2*)&r0;
            const __half2* p1 = (const __half2*)&r1;
#pragma unroll
            for (int j = 0; j < 4; j++) {
                float2 f0 = __half22float2(p0[j]);
                float2 f1 = __half22float2(p1[j]);
                acc[2 * j]     = fmaf(a0, f0.x, acc[2 * j]);
                acc[2 * j + 1] = fmaf(a0, f0.y, acc[2 * j + 1]);
                acc[2 * j]     = fmaf(a1, f1.x, acc[2 * j]);
                acc[2 * j + 1] = fmaf(a1, f1.y, acc[2 * j + 1]);
            }
        }
        for (; e < deg; e += 8) {
            int o0 = srcbuf[e];
            int4 r0 = *(const int4*)(hb + o0);
            float a0 = al[e];
            const __half2* p0 = (const __half2*)&r0;
#pragma unroll
            for (int j = 0; j < 4; j++) {
                float2 f0 = __half22float2(p0[j]);
                acc[2 * j]     = fmaf(a0, f0.x, acc[2 * j]);
                acc[2 * j + 1] = fmaf(a0, f0.y, acc[2 * j + 1]);
            }
        }
#pragma unroll
        for (int j = 0; j < 4; j++)
            *(float2*)&pacc[g][c0 + 2 * j] = make_float2(acc[2 * j], acc[2 * j + 1]);
        __syncthreads();

        float inv = hsuminv[head];
        float sv = pacc[0][t];
#pragma unroll
        for (int g2 = 1; g2 < 8; g2++) sv += pacc[g2][t];
        v = sv * inv + bias[t];
    } else {
        // fallback (deg > DEGCAP): recompute path, never hit for this graph
        float mx = -1e30f;
        for (int j = beg + lane; j < end; j += 32) {
            int2 ce = csr[j];
            float lg = ls[ce.x * 4 + head] + ldn + __int_as_float(ce.y) * wd;
            lg = lg > 0.f ? lg : NEG * lg;
            mx = fmaxf(mx, lg);
        }
        for (int o = 16; o; o >>= 1) mx = fmaxf(mx, __shfl_xor(mx, o, 32));
        float sum = 0.f, acc = 0.f;
        for (int j = beg; j < end; j++) {
            int2 ce = csr[j];
            float lg = ls[ce.x * 4 + head] + ldn + __int_as_float(ce.y) * wd;
            lg = lg > 0.f ? lg : NEG * lg;
            float p = __expf(lg - mx);
            sum += p;
            acc = fmaf(p, __half2float(h[(size_t)ce.x * HC + t]), acc);
        }
        v = acc / (sum + 1e-16f) + bias[t];
    }

    if (RELU) v = fmaxf(v, 0.f);
    if (!FUSE3) out[(size_t)nid * HC + t] = v;   // FUSE3: only h3 consumed downstream

    if (FUSE3) {
        float p = v * W3[t];
        for (int o = 32; o; o >>= 1) p += __shfl_xor(p, o, 64);
        __shared__ float sh[2];
        if ((t & 63) == 0) sh[t >> 6] = p;
        __syncthreads();
        if (t == 0) h3[nid] = sh[0] + sh[1];
    }
}

// ---------------- layer 3 (1 head, 1 channel), 8 lanes per node ----------------
__global__ __launch_bounds__(256) void layer3_k(
        const float* __restrict__ h3, const int* __restrict__ row_ptr,
        const int2* __restrict__ csr,
        const float* __restrict__ wedot, const float* __restrict__ as3,
        const float* __restrict__ ad3, const float* __restrict__ b3,
        float* __restrict__ out, int n) {
    int idx = blockIdx.x * blockDim.x + threadIdx.x;
    int node = idx >> 3, l = idx & 7;
    if (node >= n) return;
    float A = as3[0], D = ad3[0], wd = wedot[8];
    int beg = row_ptr[node], end = row_ptr[node + 1];
    float hdn = h3[node] * D;

    float mx = -1e30f;
    for (int j = beg + l; j < end; j += 8) {
        int2 ce = csr[j];
        float lg = h3[ce.x] * A + hdn + __int_as_float(ce.y) * wd;
        lg = lg > 0.f ? lg : NEG * lg;
        mx = fmaxf(mx, lg);
    }
    mx = fmaxf(mx, __shfl_xor(mx, 1, 8));
    mx = fmaxf(mx, __shfl_xor(mx, 2, 8));
    mx = fmaxf(mx, __shfl_xor(mx, 4, 8));

    float sum = 0.f, num = 0.f;
    for (int j = beg + l; j < end; j += 8) {
        int2 ce = csr[j];
        float hv = h3[ce.x];
        float lg = hv * A + hdn + __int_as_float(ce.y) * wd;
        lg = lg > 0.f ? lg : NEG * lg;
        float p = __expf(lg - mx);
        sum += p;
        num = fmaf(p, hv, num);
    }
    sum += __shfl_xor(sum, 1, 8); num += __shfl_xor(num, 1, 8);
    sum += __shfl_xor(sum, 2, 8); num += __shfl_xor(num, 2, 8);
    sum += __shfl_xor(sum, 4, 8); num += __shfl_xor(num, 4, 8);
    if (l == 0) out[node] = num / (sum + 1e-16f) + b3[0];
}

// ---------------- launch ----------------

extern "C" void kernel_launch(void* const* d_in, const int* in_sizes, int n_in,
                              void* d_out, int out_size, void* d_ws, size_t ws_size,
                              hipStream_t stream) {
    const float* x   = (const float*)d_in[0];
    const int*   ei  = (const int*)d_in[1];
    const float* ea  = (const float*)d_in[2];
    const float* W1  = (const float*)d_in[3];
    const float* We1 = (const float*)d_in[4];
    const float* as1 = (const float*)d_in[5];
    const float* ad1 = (const float*)d_in[6];
    const float* ae1 = (const float*)d_in[7];
    const float* b1  = (const float*)d_in[8];
    const float* W2  = (const float*)d_in[9];
    const float* We2 = (const float*)d_in[10];
    const float* as2 = (const float*)d_in[11];
    const float* ad2 = (const float*)d_in[12];
    const float* ae2 = (const float*)d_in[13];
    const float* b2  = (const float*)d_in[14];
    const float* W3  = (const float*)d_in[15];
    const float* We3 = (const float*)d_in[16];
    const float* as3 = (const float*)d_in[17];
    const float* ad3 = (const float*)d_in[18];
    const float* ae3 = (const float*)d_in[19];
    const float* b3  = (const float*)d_in[20];

    const int N = NNODES, E = NEDGES, etot = ETOT;

    char* ws = (char*)d_ws;
    size_t o = 0;
    auto alloc = [&](size_t bytes) { size_t r = o; o = (o + bytes + 255) & ~(size_t)255; return r; };
    size_t o_deg   = alloc((size_t)N * 4);
    size_t zero_span = o;
    size_t o_rp    = alloc((size_t)(N + 1) * 4);
    size_t o_bsum  = alloc(256 * 4);
    size_t o_wd    = alloc(16 * 4);
    size_t o_rank  = alloc((size_t)E * 4);
    size_t o_csr   = alloc((size_t)etot * 8);
    size_t o_ls    = alloc((size_t)N * 4 * 4);
    size_t o_ld    = alloc((size_t)N * 4 * 4);
    size_t o_h3    = alloc((size_t)N * 4);
    size_t o_h16   = alloc((size_t)N * HC * 2);   // fp16 feature rows (both layers)
    size_t o_bufB  = alloc((size_t)N * HC * 4);   // fp32 agg-1 output

    int*    deg   = (int*)(ws + o_deg);
    int*    rp    = (int*)(ws + o_rp);
    int*    bsum  = (int*)(ws + o_bsum);
    float*  wd    = (float*)(ws + o_wd);
    int*    rank  = (int*)(ws + o_rank);
    int2*   csr   = (int2*)(ws + o_csr);
    float*  ls    = (float*)(ws + o_ls);
    float*  ld_   = (float*)(ws + o_ld);
    float*  h3    = (float*)(ws + o_h3);
    __half* h16   = (__half*)(ws + o_h16);
    float*  bufB  = (float*)(ws + o_bufB);

    hipMemsetAsync(ws, 0, zero_span, stream);

    int nb = (N + 255) / 256;
    rank_k<<<(E + 255) / 256, 256, 0, stream>>>(ei, rank, deg, E);
    scan_block<<<nb, 256, 0, stream>>>(deg, rp, bsum, N);
    scan_top<<<1, 256, 0, stream>>>(bsum, nb);
    scan_add<<<(N + 256) / 256, 256, 0, stream>>>(rp, bsum, N, etot);
    scatter_k<<<(E + 255) / 256, 256, 0, stream>>>(ei, ea, rp, rank, csr, E);
    selfloop_k<<<(N * 8 + 255) / 256, 256, 0, stream>>>(rp, csr, N);
    wedot_k<<<1, 128, 0, stream>>>(We1, ae1, We2, ae2, We3, ae3, wd);

    // layer 1
    gemm_lsld<FIN><<<(N + 63) / 64, 256, 0, stream>>>(x, W1, as1, ad1, h16, ls, ld_, N);
    agg_k<true, false><<<N, 128, 0, stream>>>(h16, ls, ld_, rp, csr, wd, b1,
                                              bufB, nullptr, nullptr, N);
    // layer 2 (+ fused layer-3 projection)
    gemm_lsld<HC><<<(N + 63) / 64, 256, 0, stream>>>(bufB, W2, as2, ad2, h16, ls, ld_, N);
    agg_k<true, true><<<N, 128, 0, stream>>>(h16, ls, ld_, rp, csr, wd + 4, b2,
                                             nullptr, W3, h3, N);
    // layer 3
    layer3_k<<<(N * 8 + 255) / 256, 256, 0, stream>>>(h3, rp, csr, wd, as3, ad3, b3,
                                                      (float*)d_out, N);
}

// Round 8
// 303.299 us; speedup vs baseline: 3.2883x; 1.1513x over previous
//
#include <hip/hip_runtime.h>
#include <hip/hip_bf16.h>
#include <hip/hip_fp16.h>

#define NNODES 50000
#define NEDGES 1600000
#define ETOT   (NNODES + NEDGES)
#define FIN    256
#define HC     128
#define NEG    0.2f
#define DEGCAP 128
#define ALP    (DEGCAP + 8)

// ---------------- shared GEMM body (register-blocked, h stored fp16) ----------------
template <int K>
__device__ __forceinline__ void gemm_body(
        const float* __restrict__ x, const float* __restrict__ W,
        const float* __restrict__ a_s, const float* __restrict__ a_d,
        __half* __restrict__ h, float* __restrict__ ls, float* __restrict__ ld_,
        int n, int bid) {
    constexpr int BM = 64, BK = 32;
    __shared__ float xsT[BK][BM];   // element (k,m) at xsT[k][m ^ ((k&7)<<2)]
    __shared__ float ws[BK][HC];
    int t = threadIdx.x;
    int tx = t & 31;
    int ty = t >> 5;
    int r0 = bid * BM;

    float acc[8][4];
#pragma unroll
    for (int r = 0; r < 8; r++)
#pragma unroll
        for (int c = 0; c < 4; c++) acc[r][c] = 0.f;

    for (int kc = 0; kc < K; kc += BK) {
        __syncthreads();
#pragma unroll
        for (int q = 0; q < 2; q++) {
            int idx = q * 256 + t;
            int m = idx >> 3;
            int k4 = (idx & 7) * 4;
            int row = r0 + m;
            float4 v = (row < n) ? *(const float4*)&x[(size_t)row * K + kc + k4]
                                 : make_float4(0.f, 0.f, 0.f, 0.f);
            float vv[4] = {v.x, v.y, v.z, v.w};
#pragma unroll
            for (int j = 0; j < 4; j++) {
                int k = k4 + j;
                xsT[k][m ^ ((k & 7) << 2)] = vv[j];
            }
        }
#pragma unroll
        for (int q = 0; q < 4; q++) {
            int idx = q * 256 + t;
            int k = idx >> 5;
            int n4 = (idx & 31) * 4;
            *(float4*)&ws[k][n4] = *(const float4*)&W[(size_t)(kc + k) * HC + n4];
        }
        __syncthreads();
#pragma unroll
        for (int kk = 0; kk < BK; kk++) {
            int s = (kk & 7) << 2;
            float4 a0 = *(const float4*)&xsT[kk][(8 * ty) ^ s];
            float4 a1 = *(const float4*)&xsT[kk][(8 * ty + 4) ^ s];
            float4 w0 = *(const float4*)&ws[kk][4 * tx];
            float a[8] = {a0.x, a0.y, a0.z, a0.w, a1.x, a1.y, a1.z, a1.w};
            float wv[4] = {w0.x, w0.y, w0.z, w0.w};
#pragma unroll
            for (int r = 0; r < 8; r++)
#pragma unroll
                for (int c = 0; c < 4; c++)
                    acc[r][c] = fmaf(a[r], wv[c], acc[r][c]);
        }
    }

    int head = tx >> 3;
    float4 sa4 = *(const float4*)&a_s[4 * tx];
    float4 sd4 = *(const float4*)&a_d[4 * tx];
    float sa[4] = {sa4.x, sa4.y, sa4.z, sa4.w};
    float sd[4] = {sd4.x, sd4.y, sd4.z, sd4.w};
#pragma unroll
    for (int r = 0; r < 8; r++) {
        int row = r0 + 8 * ty + r;
        if (row >= n) break;
        union { __half2 h2[2]; int2 i2; } u;
        u.h2[0] = __floats2half2_rn(acc[r][0], acc[r][1]);
        u.h2[1] = __floats2half2_rn(acc[r][2], acc[r][3]);
        *(int2*)&h[(size_t)row * HC + 4 * tx] = u.i2;
        float p = acc[r][0] * sa[0] + acc[r][1] * sa[1] + acc[r][2] * sa[2] + acc[r][3] * sa[3];
        float q = acc[r][0] * sd[0] + acc[r][1] * sd[1] + acc[r][2] * sd[2] + acc[r][3] * sd[3];
        p += __shfl_xor(p, 1); q += __shfl_xor(q, 1);
        p += __shfl_xor(p, 2); q += __shfl_xor(q, 2);
        p += __shfl_xor(p, 4); q += __shfl_xor(q, 4);
        if ((tx & 7) == 0) {
            ls[row * 4 + head] = p;
            ld_[row * 4 + head] = q;
        }
    }
}

// ---------------- fused: gemm layer-1 | edge ranking | wedot ----------------
// blocks [0, gB): gemm tiles; [gB, gB+rB): rank chunks; block gB+rB: wedot.
__global__ __launch_bounds__(256) void gemm1_rank_fused(
        const float* __restrict__ x, const float* __restrict__ W,
        const float* __restrict__ a_s, const float* __restrict__ a_d,
        __half* __restrict__ h, float* __restrict__ ls, float* __restrict__ ld_,
        int n,
        const int* __restrict__ ei, int* __restrict__ rank, int* __restrict__ deg, int E,
        const float* We1, const float* ae1, const float* We2, const float* ae2,
        const float* We3, const float* ae3, float* __restrict__ wedot,
        int gB, int rB) {
    int b = blockIdx.x;
    if (b < gB) {
        gemm_body<FIN>(x, W, a_s, a_d, h, ls, ld_, n, b);
    } else if (b < gB + rB) {
        int i = (b - gB) * 256 + threadIdx.x;
        if (i < E) rank[i] = atomicAdd(&deg[ei[E + i]], 1);
    } else {
        int t = threadIdx.x;
        if (t < 128) {
            float p1 = We1[t] * ae1[t];
            float p2 = We2[t] * ae2[t];
            for (int o = 16; o; o >>= 1) {
                p1 += __shfl_xor(p1, o, 32);
                p2 += __shfl_xor(p2, o, 32);
            }
            if ((t & 31) == 0) {
                wedot[t >> 5] = p1;
                wedot[4 + (t >> 5)] = p2;
            }
            if (t == 0) wedot[8] = We3[0] * ae3[0];
        }
    }
}

// standalone gemm (layer 2)
template <int K>
__global__ __launch_bounds__(256) void gemm_lsld(
        const float* __restrict__ x, const float* __restrict__ W,
        const float* __restrict__ a_s, const float* __restrict__ a_d,
        __half* __restrict__ h, float* __restrict__ ls, float* __restrict__ ld_,
        int n) {
    gemm_body<K>(x, W, a_s, a_d, h, ls, ld_, n, blockIdx.x);
}

// ---------------- CSR build ----------------

// exclusive scan of (deg[i]+1)  — +1 reserves the self-loop slot per node
__global__ void scan_block(const int* __restrict__ deg, int* __restrict__ out,
                           int* __restrict__ bsum, int n) {
    __shared__ int sh[256];
    int t = threadIdx.x;
    int i = blockIdx.x * 256 + t;
    int v = (i < n) ? (deg[i] + 1) : 0;
    sh[t] = v;
    __syncthreads();
    for (int o = 1; o < 256; o <<= 1) {
        int a = (t >= o) ? sh[t - o] : 0;
        __syncthreads();
        sh[t] += a;
        __syncthreads();
    }
    if (i < n) out[i] = sh[t] - v;
    if (t == 255) bsum[blockIdx.x] = sh[255];
}

__global__ void scan_top(int* __restrict__ bsum, int nb) {
    __shared__ int sh[256];
    int t = threadIdx.x;
    int v = (t < nb) ? bsum[t] : 0;
    sh[t] = v;
    __syncthreads();
    for (int o = 1; o < 256; o <<= 1) {
        int a = (t >= o) ? sh[t - o] : 0;
        __syncthreads();
        sh[t] += a;
        __syncthreads();
    }
    if (t < nb) bsum[t] = sh[t] - v;
}

__global__ void scan_add(int* __restrict__ rp, const int* __restrict__ boff,
                         int n, int etot) {
    int i = blockIdx.x * blockDim.x + threadIdx.x;
    if (i < n)      rp[i] += boff[i >> 8];
    else if (i == n) rp[n] = etot;
}

// atomic-free scatter into packed (src, ea) int2 CSR
__global__ void scatter_k(const int* __restrict__ ei, const float* __restrict__ ea,
                          const int* __restrict__ rp, const int* __restrict__ rank,
                          int2* __restrict__ csr, int E) {
    int i = blockIdx.x * blockDim.x + threadIdx.x;
    if (i < E) {
        int d = ei[E + i];
        int pos = rp[d] + rank[i];
        csr[pos] = make_int2(ei[i], __float_as_int(ea[i]));
    }
}

// self-loop slot: 8 lanes per node
__global__ __launch_bounds__(256) void selfloop_k(const int* __restrict__ rp,
                                                  int2* __restrict__ csr, int n) {
    int idx = blockIdx.x * blockDim.x + threadIdx.x;
    int node = idx >> 3, l = idx & 7;
    if (node >= n) return;
    int beg = rp[node], end = rp[node + 1] - 1;
    float s = 0.f;
    for (int j = beg + l; j < end; j += 8) s += __int_as_float(csr[j].y);
    s += __shfl_xor(s, 1, 8);
    s += __shfl_xor(s, 2, 8);
    s += __shfl_xor(s, 4, 8);
    if (l == 0)
        csr[end] = make_int2(node, __float_as_int(s / fmaxf((float)(end - beg), 1.0f)));
}

// ---------------- per-node softmax aggregation (fp16 full-row gather) ----------------
template <bool RELU, bool FUSE3>
__global__ __launch_bounds__(128) void agg_k(
        const __half* __restrict__ h, const float* __restrict__ ls,
        const float* __restrict__ ld_, const int* __restrict__ row_ptr,
        const int2* __restrict__ csr,
        const float* __restrict__ wedot, const float* __restrict__ bias,
        float* __restrict__ out, const float* __restrict__ W3,
        float* __restrict__ h3, int n) {
    __shared__ float albuf[4][ALP];
    __shared__ int srcbuf[DEGCAP];       // pre-scaled row byte offsets (s*256)
    __shared__ float pacc[8][HC];
    __shared__ float hsuminv[4];
    int nid = blockIdx.x;
    int t = threadIdx.x, head = t >> 5, lane = t & 31;
    int beg = row_ptr[nid], end = row_ptr[nid + 1];
    int deg = end - beg;
    float ldn = ld_[nid * 4 + head];
    float wd = wedot[head];

    float v;
    if (deg <= DEGCAP) {
        // phase A: logits in registers, per-head max; head-0 wave caches byte offsets
        float lgr[4];
        float mx = -1e30f;
#pragma unroll
        for (int i = 0; i < 4; i++) {
            int e = lane + 32 * i;
            float lg = -1e30f;
            if (e < deg) {
                int2 ce = csr[beg + e];
                if (head == 0) srcbuf[e] = ce.x << 8;   // s * HC * 2 bytes
                lg = ls[ce.x * 4 + head] + ldn + __int_as_float(ce.y) * wd;
                lg = lg > 0.f ? lg : NEG * lg;
            }
            lgr[i] = lg;
            mx = fmaxf(mx, lg);
        }
        for (int o = 16; o; o >>= 1) mx = fmaxf(mx, __shfl_xor(mx, o, 32));

        // phase B: exp -> albuf, per-head sum
        float sum = 0.f;
#pragma unroll
        for (int i = 0; i < 4; i++) {
            int e = lane + 32 * i;
            if (e < deg) {
                float p = __expf(lgr[i] - mx);
                albuf[head][e] = p;
                sum += p;
            }
        }
        for (int o = 16; o; o >>= 1) sum += __shfl_xor(sum, o, 32);
        if (lane == 0) hsuminv[head] = 1.f / (sum + 1e-16f);
        __syncthreads();

        // phase C: 8 groups x 16 lanes; group g -> edges g, g+8, ...
        int g = t >> 4, l = t & 15;
        int c0 = 8 * l;
        const float* al = albuf[c0 >> 5];
        const char* hb = (const char*)h + 16 * l;
        float acc[8];
#pragma unroll
        for (int j = 0; j < 8; j++) acc[j] = 0.f;
        int e = g;
        for (; e + 8 < deg; e += 16) {
            int o0 = srcbuf[e], o1 = srcbuf[e + 8];
            int4 r0 = *(const int4*)(hb + o0);
            int4 r1 = *(const int4*)(hb + o1);
            float a0 = al[e], a1 = al[e + 8];
            const __half2* p0 = (const __half2*)&r0;
            const __half2* p1 = (const __half2*)&r1;
#pragma unroll
            for (int j = 0; j < 4; j++) {
                float2 f0 = __half22float2(p0[j]);
                float2 f1 = __half22float2(p1[j]);
                acc[2 * j]     = fmaf(a0, f0.x, acc[2 * j]);
                acc[2 * j + 1] = fmaf(a0, f0.y, acc[2 * j + 1]);
                acc[2 * j]     = fmaf(a1, f1.x, acc[2 * j]);
                acc[2 * j + 1] = fmaf(a1, f1.y, acc[2 * j + 1]);
            }
        }
        for (; e < deg; e += 8) {
            int o0 = srcbuf[e];
            int4 r0 = *(const int4*)(hb + o0);
            float a0 = al[e];
            const __half2* p0 = (const __half2*)&r0;
#pragma unroll
            for (int j = 0; j < 4; j++) {
                float2 f0 = __half22float2(p0[j]);
                acc[2 * j]     = fmaf(a0, f0.x, acc[2 * j]);
                acc[2 * j + 1] = fmaf(a0, f0.y, acc[2 * j + 1]);
            }
        }
#pragma unroll
        for (int j = 0; j < 4; j++)
            *(float2*)&pacc[g][c0 + 2 * j] = make_float2(acc[2 * j], acc[2 * j + 1]);
        __syncthreads();

        float inv = hsuminv[head];
        float sv = pacc[0][t];
#pragma unroll
        for (int g2 = 1; g2 < 8; g2++) sv += pacc[g2][t];
        v = sv * inv + bias[t];
    } else {
        // fallback (deg > DEGCAP): recompute path, never hit for this graph
        float mx = -1e30f;
        for (int j = beg + lane; j < end; j += 32) {
            int2 ce = csr[j];
            float lg = ls[ce.x * 4 + head] + ldn + __int_as_float(ce.y) * wd;
            lg = lg > 0.f ? lg : NEG * lg;
            mx = fmaxf(mx, lg);
        }
        for (int o = 16; o; o >>= 1) mx = fmaxf(mx, __shfl_xor(mx, o, 32));
        float sum = 0.f, acc = 0.f;
        for (int j = beg; j < end; j++) {
            int2 ce = csr[j];
            float lg = ls[ce.x * 4 + head] + ldn + __int_as_float(ce.y) * wd;
            lg = lg > 0.f ? lg : NEG * lg;
            float p = __expf(lg - mx);
            sum += p;
            acc = fmaf(p, __half2float(h[(size_t)ce.x * HC + t]), acc);
        }
        v = acc / (sum + 1e-16f) + bias[t];
    }

    if (RELU) v = fmaxf(v, 0.f);
    if (!FUSE3) out[(size_t)nid * HC + t] = v;   // FUSE3: only h3 consumed downstream

    if (FUSE3) {
        float p = v * W3[t];
        for (int o = 32; o; o >>= 1) p += __shfl_xor(p, o, 64);
        __shared__ float sh[2];
        if ((t & 63) == 0) sh[t >> 6] = p;
        __syncthreads();
        if (t == 0) h3[nid] = sh[0] + sh[1];
    }
}

// ---------------- layer 3 (1 head, 1 channel), 8 lanes per node ----------------
__global__ __launch_bounds__(256) void layer3_k(
        const float* __restrict__ h3, const int* __restrict__ row_ptr,
        const int2* __restrict__ csr,
        const float* __restrict__ wedot, const float* __restrict__ as3,
        const float* __restrict__ ad3, const float* __restrict__ b3,
        float* __restrict__ out, int n) {
    int idx = blockIdx.x * blockDim.x + threadIdx.x;
    int node = idx >> 3, l = idx & 7;
    if (node >= n) return;
    float A = as3[0], D = ad3[0], wd = wedot[8];
    int beg = row_ptr[node], end = row_ptr[node + 1];
    float hdn = h3[node] * D;

    float mx = -1e30f;
    for (int j = beg + l; j < end; j += 8) {
        int2 ce = csr[j];
        float lg = h3[ce.x] * A + hdn + __int_as_float(ce.y) * wd;
        lg = lg > 0.f ? lg : NEG * lg;
        mx = fmaxf(mx, lg);
    }
    mx = fmaxf(mx, __shfl_xor(mx, 1, 8));
    mx = fmaxf(mx, __shfl_xor(mx, 2, 8));
    mx = fmaxf(mx, __shfl_xor(mx, 4, 8));

    float sum = 0.f, num = 0.f;
    for (int j = beg + l; j < end; j += 8) {
        int2 ce = csr[j];
        float hv = h3[ce.x];
        float lg = hv * A + hdn + __int_as_float(ce.y) * wd;
        lg = lg > 0.f ? lg : NEG * lg;
        float p = __expf(lg - mx);
        sum += p;
        num = fmaf(p, hv, num);
    }
    sum += __shfl_xor(sum, 1, 8); num += __shfl_xor(num, 1, 8);
    sum += __shfl_xor(sum, 2, 8); num += __shfl_xor(num, 2, 8);
    sum += __shfl_xor(sum, 4, 8); num += __shfl_xor(num, 4, 8);
    if (l == 0) out[node] = num / (sum + 1e-16f) + b3[0];
}

// ---------------- launch ----------------

extern "C" void kernel_launch(void* const* d_in, const int* in_sizes, int n_in,
                              void* d_out, int out_size, void* d_ws, size_t ws_size,
                              hipStream_t stream) {
    const float* x   = (const float*)d_in[0];
    const int*   ei  = (const int*)d_in[1];
    const float* ea  = (const float*)d_in[2];
    const float* W1  = (const float*)d_in[3];
    const float* We1 = (const float*)d_in[4];
    const float* as1 = (const float*)d_in[5];
    const float* ad1 = (const float*)d_in[6];
    const float* ae1 = (const float*)d_in[7];
    const float* b1  = (const float*)d_in[8];
    const float* W2  = (const float*)d_in[9];
    const float* We2 = (const float*)d_in[10];
    const float* as2 = (const float*)d_in[11];
    const float* ad2 = (const float*)d_in[12];
    const float* ae2 = (const float*)d_in[13];
    const float* b2  = (const float*)d_in[14];
    const float* W3  = (const float*)d_in[15];
    const float* We3 = (const float*)d_in[16];
    const float* as3 = (const float*)d_in[17];
    const float* ad3 = (const float*)d_in[18];
    const float* ae3 = (const float*)d_in[19];
    const float* b3  = (const float*)d_in[20];

    const int N = NNODES, E = NEDGES, etot = ETOT;

    char* ws = (char*)d_ws;
    size_t o = 0;
    auto alloc = [&](size_t bytes) { size_t r = o; o = (o + bytes + 255) & ~(size_t)255; return r; };
    size_t o_deg   = alloc((size_t)N * 4);
    size_t zero_span = o;
    size_t o_rp    = alloc((size_t)(N + 1) * 4);
    size_t o_bsum  = alloc(256 * 4);
    size_t o_wd    = alloc(16 * 4);
    size_t o_rank  = alloc((size_t)E * 4);
    size_t o_csr   = alloc((size_t)etot * 8);
    size_t o_ls    = alloc((size_t)N * 4 * 4);
    size_t o_ld    = alloc((size_t)N * 4 * 4);
    size_t o_h3    = alloc((size_t)N * 4);
    size_t o_h16   = alloc((size_t)N * HC * 2);   // fp16 feature rows (both layers)
    size_t o_bufB  = alloc((size_t)N * HC * 4);   // fp32 agg-1 output

    int*    deg   = (int*)(ws + o_deg);
    int*    rp    = (int*)(ws + o_rp);
    int*    bsum  = (int*)(ws + o_bsum);
    float*  wd    = (float*)(ws + o_wd);
    int*    rank  = (int*)(ws + o_rank);
    int2*   csr   = (int2*)(ws + o_csr);
    float*  ls    = (float*)(ws + o_ls);
    float*  ld_   = (float*)(ws + o_ld);
    float*  h3    = (float*)(ws + o_h3);
    __half* h16   = (__half*)(ws + o_h16);
    float*  bufB  = (float*)(ws + o_bufB);

    hipMemsetAsync(ws, 0, zero_span, stream);

    int gB = (N + 63) / 64;          // 782 gemm tiles
    int rB = (E + 255) / 256;        // 6250 rank chunks
    int nb = (N + 255) / 256;

    // fused: gemm layer-1 || edge ranking || wedot
    gemm1_rank_fused<<<gB + rB + 1, 256, 0, stream>>>(
        x, W1, as1, ad1, h16, ls, ld_, N,
        ei, rank, deg, E,
        We1, ae1, We2, ae2, We3, ae3, wd, gB, rB);

    scan_block<<<nb, 256, 0, stream>>>(deg, rp, bsum, N);
    scan_top<<<1, 256, 0, stream>>>(bsum, nb);
    scan_add<<<(N + 256) / 256, 256, 0, stream>>>(rp, bsum, N, etot);
    scatter_k<<<(E + 255) / 256, 256, 0, stream>>>(ei, ea, rp, rank, csr, E);
    selfloop_k<<<(N * 8 + 255) / 256, 256, 0, stream>>>(rp, csr, N);

    // layer 1 aggregation
    agg_k<true, false><<<N, 128, 0, stream>>>(h16, ls, ld_, rp, csr, wd, b1,
                                              bufB, nullptr, nullptr, N);
    // layer 2 (+ fused layer-3 projection)
    gemm_lsld<HC><<<(N + 63) / 64, 256, 0, stream>>>(bufB, W2, as2, ad2, h16, ls, ld_, N);
    agg_k<true, true><<<N, 128, 0, stream>>>(h16, ls, ld_, rp, csr, wd + 4, b2,
                                             nullptr, W3, h3, N);
    // layer 3
    layer3_k<<<(N * 8 + 255) / 256, 256, 0, stream>>>(h3, rp, csr, wd, as3, ad3, b3,
                                                      (float*)d_out, N);
}